// Round 8
// baseline (774.107 us; speedup 1.0000x reference)
//
#include <hip/hip_runtime.h>

#define N_MET 250000
#define N_RXN 500000
#define N_RXN_PAD 500032   // padded rows for T so MFMA tail tiles stay in-bounds
#define E_SUB 2000000
#define E_ALL 4000000
#define DT 0.01f
#define NXCD 8

#define RXN_PER_BLK 256
#define THREADS 256
#define EDGE_CAP 1536   // Poisson(1024) +16 sigma; global fallback below

#define MV_RPB 64       // k_mv reactions per block (4 waves x 16)

#define SCAN_T 256
#define SCAN_V 8
#define SCAN_CHUNK (SCAN_T * SCAN_V)
#define SCAN_NB ((N_RXN + SCAN_CHUNK - 1) / SCAN_CHUNK)
static_assert(SCAN_NB <= SCAN_T, "scan2 single block must cover all block sums");

typedef int v4i __attribute__((ext_vector_type(4)));
typedef float v4f __attribute__((ext_vector_type(4)));
typedef short bf16x8 __attribute__((ext_vector_type(8)));
typedef float f32x4 __attribute__((ext_vector_type(4)));

static __device__ __forceinline__ float fast_tanh(float x) {
  float e = __expf(x + x);
  return 1.0f - __fdividef(2.0f, e + 1.0f);
}

static __device__ __forceinline__ void atomic_add_f32(float* p, float v) {
  __hip_atomic_fetch_add(p, v, __ATOMIC_RELAXED, __HIP_MEMORY_SCOPE_AGENT);
}
// XCD-local atomic: executes in the local TCC (no cross-XCD bypass). Only valid
// when every writer of the target line is on the same XCD (per-XCD partials).
static __device__ __forceinline__ void atomic_add_l2f(float* p, float v) {
  __hip_atomic_fetch_add(p, v, __ATOMIC_RELAXED, __HIP_MEMORY_SCOPE_WORKGROUP);
}
static __device__ __forceinline__ void atomic_add_l2i(int* p, int v) {
  __hip_atomic_fetch_add(p, v, __ATOMIC_RELAXED, __HIP_MEMORY_SCOPE_WORKGROUP);
}

// physical XCD id (0..7): hwreg id 20 (HW_REG_XCC_ID), offset 0, width 4
static __device__ __forceinline__ int xcc_id() {
  return __builtin_amdgcn_s_getreg(20 | (3 << 11)) & (NXCD - 1);
}

static __device__ __forceinline__ int bcast_i(int v, int lane) {
  return __builtin_amdgcn_readlane(v, lane);
}

static __device__ __forceinline__ unsigned short bf16_rn(float f) {
  unsigned u = __float_as_uint(f);
  unsigned r = u + 0x7FFFu + ((u >> 16) & 1u);
  return (unsigned short)(r >> 16);
}

// ---- precompute MFMA B-fragments of W23 = W2@W3 (bf16 hi/lo) and b2@W3 ----
__global__ void k_pre(const float* __restrict__ W2, const float* __restrict__ W3,
                      const float* __restrict__ b2,
                      uint4* __restrict__ wfh, uint4* __restrict__ wfl,
                      float* __restrict__ b2w3) {
  int tid = blockIdx.x * blockDim.x + threadIdx.x;
  if (tid < 512) {
    int lane = tid & 63, jt = (tid >> 6) & 3, ks = tid >> 8;
    int jj = jt * 16 + (lane & 15);
    unsigned short h[8], l[8];
    #pragma unroll
    for (int t = 0; t < 8; ++t) {
      int kk = ks * 32 + (lane >> 4) * 8 + t;
      float w = 0.f;
      #pragma unroll
      for (int m = 0; m < 32; ++m) w = fmaf(W2[kk * 32 + m], W3[m * 64 + jj], w);
      h[t] = bf16_rn(w);
      float hf = __uint_as_float(((unsigned)h[t]) << 16);
      l[t] = bf16_rn(w - hf);
    }
    uint4 H, L;
    H.x = (unsigned)h[0] | ((unsigned)h[1] << 16);
    H.y = (unsigned)h[2] | ((unsigned)h[3] << 16);
    H.z = (unsigned)h[4] | ((unsigned)h[5] << 16);
    H.w = (unsigned)h[6] | ((unsigned)h[7] << 16);
    L.x = (unsigned)l[0] | ((unsigned)l[1] << 16);
    L.y = (unsigned)l[2] | ((unsigned)l[3] << 16);
    L.z = (unsigned)l[4] | ((unsigned)l[5] << 16);
    L.w = (unsigned)l[6] | ((unsigned)l[7] << 16);
    int idx = (ks * 4 + jt) * 64 + lane;
    wfh[idx] = H; wfl[idx] = L;
  }
  if (tid < 64) {
    float t = 0.f;
    #pragma unroll
    for (int m = 0; m < 32; ++m) t = fmaf(b2[m], W3[m * 64 + tid], t);
    b2w3[tid] = t;
  }
}

// ---- histogram (per-XCD partials) + dense conc extraction ----
__global__ void k_hist(const int* __restrict__ rxn_sub, const float* __restrict__ x,
                       int* __restrict__ counts, int* __restrict__ counts_part,
                       float* __restrict__ conc, int use_part) {
  int t = blockIdx.x * blockDim.x + threadIdx.x;
  if (t < E_SUB / 4) {
    v4i r = __builtin_nontemporal_load((const v4i*)rxn_sub + t);
    if (use_part) {
      int* cp = counts_part + (size_t)xcc_id() * N_RXN;
      atomic_add_l2i(&cp[r.x], 1);
      atomic_add_l2i(&cp[r.y], 1);
      atomic_add_l2i(&cp[r.z], 1);
      atomic_add_l2i(&cp[r.w], 1);
    } else {
      atomicAdd(&counts[r.x], 1);
      atomicAdd(&counts[r.y], 1);
      atomicAdd(&counts[r.z], 1);
      atomicAdd(&counts[r.w], 1);
    }
  }
  if (t < N_MET) conc[t] = __builtin_nontemporal_load(x + t * 8 + 3);
}

__global__ void k_sumc(const int* __restrict__ counts_part, int* __restrict__ counts) {
  int i = blockIdx.x * blockDim.x + threadIdx.x;
  if (i < N_RXN) {
    int s = 0;
    #pragma unroll
    for (int xd = 0; xd < NXCD; ++xd) s += counts_part[(size_t)xd * N_RXN + i];
    counts[i] = s;
  }
}

__global__ void k_scan1(const int* __restrict__ counts, int* __restrict__ bsums) {
  __shared__ int ss[SCAN_T];
  int b = blockIdx.x, t = threadIdx.x;
  int base = b * SCAN_CHUNK + t * SCAN_V;
  int s = 0;
  #pragma unroll
  for (int k = 0; k < SCAN_V; ++k) { int i = base + k; if (i < N_RXN) s += counts[i]; }
  ss[t] = s; __syncthreads();
  for (int d = SCAN_T / 2; d > 0; d >>= 1) {
    if (t < d) ss[t] += ss[t + d];
    __syncthreads();
  }
  if (t == 0) bsums[b] = ss[0];
}

__global__ void k_scan2(int* __restrict__ bsums) {
  __shared__ int ss[SCAN_T];
  int t = threadIdx.x;
  int v = (t < SCAN_NB) ? bsums[t] : 0;
  ss[t] = v; __syncthreads();
  for (int d = 1; d < SCAN_T; d <<= 1) {
    int a = (t >= d) ? ss[t - d] : 0;
    __syncthreads();
    ss[t] += a;
    __syncthreads();
  }
  if (t < SCAN_NB) bsums[t] = ss[t] - v;  // exclusive
}

__global__ void k_scan3(const int* __restrict__ counts, const int* __restrict__ bsums,
                        int* __restrict__ off, int* __restrict__ cursor) {
  __shared__ int ss[SCAN_T];
  int b = blockIdx.x, t = threadIdx.x;
  int base = b * SCAN_CHUNK + t * SCAN_V;
  int v[SCAN_V];
  int s = 0;
  #pragma unroll
  for (int k = 0; k < SCAN_V; ++k) { int i = base + k; v[k] = (i < N_RXN) ? counts[i] : 0; s += v[k]; }
  ss[t] = s; __syncthreads();
  for (int d = 1; d < SCAN_T; d <<= 1) {
    int a = (t >= d) ? ss[t - d] : 0;
    __syncthreads();
    ss[t] += a;
    __syncthreads();
  }
  int run = bsums[b] + ss[t] - s;
  #pragma unroll
  for (int k = 0; k < SCAN_V; ++k) {
    int i = base + k;
    if (i < N_RXN) { off[i] = run; cursor[i] = run; }
    run += v[k];
  }
  if (b == 0 && t == 0) off[N_RXN] = E_SUB;
}

// ---- scatter into CSR order: 8B record per edge {m, bitcast(sto)} ----
// cursor atomics must stay agent-scope: slot uniqueness is global.
__global__ void k_scatter(const int* __restrict__ rxn_sub, const int* __restrict__ met_sub,
                          const float* __restrict__ sto_sub,
                          int* __restrict__ cursor, int2* __restrict__ edges8) {
  int e = blockIdx.x * blockDim.x + threadIdx.x;
  if (e < E_SUB) {
    int r = __builtin_nontemporal_load(rxn_sub + e);
    int m = __builtin_nontemporal_load(met_sub + e);
    float st = __builtin_nontemporal_load(sto_sub + e);
    int pos = atomicAdd(&cursor[r], 1);
    int2 rec; rec.x = m; rec.y = __float_as_int(st);
    edges8[pos] = rec;
  }
}

// ---- k_edge: wave-per-reaction edge tanh-sum; T -> bf16 hi/lo, row-major [r][64] ----
static __device__ __forceinline__ float edge_sum_lds(int o0, int o1, int estart,
                                                     const float2* ep,
                                                     float w1x, float w1y, float b1j) {
  float T0 = 0.f, T1 = 0.f;
  int c = o0;
  for (; c + 1 < o1; c += 2) {
    float2 e0 = ep[c - estart];
    float2 e1 = ep[c + 1 - estart];
    T0 += fast_tanh(fmaf(e0.x, w1x, fmaf(e0.y, w1y, b1j)));
    T1 += fast_tanh(fmaf(e1.x, w1x, fmaf(e1.y, w1y, b1j)));
  }
  if (c < o1) {
    float2 e0 = ep[c - estart];
    T0 += fast_tanh(fmaf(e0.x, w1x, fmaf(e0.y, w1y, b1j)));
  }
  return T0 + T1;
}

static __device__ __forceinline__ float edge_sum_glob(int o0, int o1,
                                                      const int2* edges8,
                                                      const float* conc,
                                                      float w1x, float w1y, float b1j) {
  float T = 0.f;
  for (int c = o0; c < o1; ++c) {
    int2 rec = edges8[c];
    float cc = conc[rec.x];
    T += fast_tanh(fmaf(cc, w1x, fmaf(__int_as_float(rec.y), w1y, b1j)));
  }
  return T;
}

__global__ __launch_bounds__(THREADS) void k_edge(
    const int* __restrict__ off, const int2* __restrict__ edges8,
    const float* __restrict__ conc,
    const float* __restrict__ W1, const float* __restrict__ b1,
    unsigned short* __restrict__ Thi, unsigned short* __restrict__ Tlo, int use_lo) {
  __shared__ int off_s[RXN_PER_BLK + 1];
  __shared__ float2 se[EDGE_CAP];

  int tid = threadIdx.x;
  int lane = tid & 63;
  int wv = tid >> 6;
  int R0 = blockIdx.x * RXN_PER_BLK;

  for (int i = tid; i <= RXN_PER_BLK; i += THREADS) {
    int r = R0 + i;
    off_s[i] = off[r > N_RXN ? N_RXN : r];
  }
  __syncthreads();
  int estart = off_s[0];
  int nE = off_s[RXN_PER_BLK] - estart;
  bool fits = (nE <= EDGE_CAP);
  if (fits) {
    for (int i = tid; i < nE; i += THREADS) {
      int2 rec = edges8[estart + i];
      se[i] = make_float2(conc[rec.x], __int_as_float(rec.y));
    }
  }

  float w1x = W1[lane], w1y = W1[64 + lane], b1j = b1[lane];

  int rbase = R0 + wv * 64;
  int o0l = off_s[wv * 64 + lane];
  int o1l = off_s[wv * 64 + lane + 1];

  __syncthreads();

  #pragma clang loop unroll(disable)
  for (int i = 0; i < 64; ++i) {
    int r = rbase + i;
    if (r >= N_RXN) break;  // uniform
    int o0 = bcast_i(o0l, i), o1 = bcast_i(o1l, i);
    float T = fits ? edge_sum_lds(o0, o1, estart, se, w1x, w1y, b1j)
                   : edge_sum_glob(o0, o1, edges8, conc, w1x, w1y, b1j);
    unsigned short hi = bf16_rn(T);
    Thi[r * 64 + lane] = hi;
    if (use_lo) {
      float hf = __uint_as_float(((unsigned)hi) << 16);
      Tlo[r * 64 + lane] = bf16_rn(T - hf);
    }
  }
}

// ---- k_mv: U = T @ W23 via MFMA (bf16 hi/lo), fused epilogue + consumption ----
__global__ __launch_bounds__(256) void k_mv(
    const int* __restrict__ off, const int2* __restrict__ edges8,
    const unsigned short* __restrict__ Thi, const unsigned short* __restrict__ Tlo,
    const uint4* __restrict__ wfh, const uint4* __restrict__ wfl,
    const float* __restrict__ b2w3, const float* __restrict__ b3,
    const float* __restrict__ W4, const float* __restrict__ b4,
    const float* __restrict__ log_k, int use_lo, int use_part,
    float* __restrict__ v_pre, float* __restrict__ total,
    float* __restrict__ total_part) {
  __shared__ int soff[MV_RPB + 1];
  int tid = threadIdx.x, lane = tid & 63, w = tid >> 6;
  int B0 = blockIdx.x * MV_RPB;
  for (int i = tid; i <= MV_RPB; i += 256) {
    int r = B0 + i;
    soff[i] = off[r > N_RXN ? N_RXN : r];
  }
  __syncthreads();

  int R0 = B0 + w * 16;
  int col = lane & 15, rowg = lane >> 4;

  bf16x8 ah[2], al[2];
  {
    int rowelem = (R0 + col) * 64 + rowg * 8;
    const uint4* ph = (const uint4*)Thi;
    ah[0] = __builtin_bit_cast(bf16x8, ph[rowelem >> 3]);
    ah[1] = __builtin_bit_cast(bf16x8, ph[(rowelem + 32) >> 3]);
    if (use_lo) {
      const uint4* pl = (const uint4*)Tlo;
      al[0] = __builtin_bit_cast(bf16x8, pl[rowelem >> 3]);
      al[1] = __builtin_bit_cast(bf16x8, pl[(rowelem + 32) >> 3]);
    }
  }

  f32x4 acc[4];
  #pragma unroll
  for (int jt = 0; jt < 4; ++jt) acc[jt] = (f32x4){0.f, 0.f, 0.f, 0.f};

  #pragma unroll
  for (int jt = 0; jt < 4; ++jt) {
    #pragma unroll
    for (int ks = 0; ks < 2; ++ks) {
      int bidx = (ks * 4 + jt) * 64 + lane;
      bf16x8 bh = __builtin_bit_cast(bf16x8, wfh[bidx]);
      acc[jt] = __builtin_amdgcn_mfma_f32_16x16x32_bf16(ah[ks], bh, acc[jt], 0, 0, 0);
      if (use_lo) {
        bf16x8 bl = __builtin_bit_cast(bf16x8, wfl[bidx]);
        acc[jt] = __builtin_amdgcn_mfma_f32_16x16x32_bf16(ah[ks], bl, acc[jt], 0, 0, 0);
        acc[jt] = __builtin_amdgcn_mfma_f32_16x16x32_bf16(al[ks], bh, acc[jt], 0, 0, 0);
      }
    }
  }

  float w4c[4], bwc[4], b3c[4];
  #pragma unroll
  for (int jt = 0; jt < 4; ++jt) {
    int jj = jt * 16 + col;
    w4c[jt] = W4[jj]; bwc[jt] = b2w3[jj]; b3c[jt] = b3[jj];
  }
  float b40 = b4[0];

  float nq[4];
  #pragma unroll
  for (int q = 0; q < 4; ++q) {
    int idx = w * 16 + rowg * 4 + q;
    nq[q] = (float)(soff[idx + 1] - soff[idx]);
  }

  float vq[4];
  #pragma unroll
  for (int q = 0; q < 4; ++q) {
    float s = 0.f;
    #pragma unroll
    for (int jt = 0; jt < 4; ++jt) {
      float u = acc[jt][q] + nq[q] * bwc[jt] + b3c[jt];
      s += fast_tanh(u) * w4c[jt];
    }
    s += __shfl_xor(s, 1, 64);
    s += __shfl_xor(s, 2, 64);
    s += __shfl_xor(s, 4, 64);
    s += __shfl_xor(s, 8, 64);
    int r = R0 + rowg * 4 + q;
    float lk = (r < N_RXN) ? log_k[r] : 0.f;
    float racc = s + b40;
    float k10 = __expf(lk * 2.3025850929940457f);
    float sp = (racc > 15.f) ? racc : __logf(1.f + __expf(racc));
    vq[q] = k10 * sp;
  }

  if (col == 0) {
    #pragma unroll
    for (int q = 0; q < 4; ++q) {
      int r = R0 + rowg * 4 + q;
      if (r < N_RXN) v_pre[r] = vq[q];
    }
  }

  // consumption: 4 lanes per reaction walk its CSR slice
  int rloc = lane >> 2;
  float vdt = vq[(lane >> 2) & 3] * DT;
  int o0 = soff[w * 16 + rloc], o1 = soff[w * 16 + rloc + 1];
  if (use_part) {
    float* tp = total_part + (size_t)xcc_id() * N_MET;
    for (int c = o0 + (lane & 3); c < o1; c += 4) {
      int2 e = edges8[c];
      atomic_add_l2f(&tp[e.x], __int_as_float(e.y) * vdt);
    }
  } else {
    for (int c = o0 + (lane & 3); c < o1; c += 4) {
      int2 e = edges8[c];
      atomic_add_f32(&total[e.x], __int_as_float(e.y) * vdt);
    }
  }
}

__global__ void k_scale(const float* __restrict__ total, const float* __restrict__ total_part,
                        const float* __restrict__ conc, float* __restrict__ met_scale,
                        int use_part) {
  int m = blockIdx.x * blockDim.x + threadIdx.x;
  if (m < N_MET) {
    float tot;
    if (use_part) {
      tot = 0.f;
      #pragma unroll
      for (int xd = 0; xd < NXCD; ++xd) tot += total_part[(size_t)xd * N_MET + m];
    } else {
      tot = total[m];
    }
    float cc = conc[m];
    met_scale[m] = (tot > 1e-12f) ? fminf(cc / tot, 1.0f) : 1.0f;
  }
}

// ---- k_rscale: per-rxn min over CSR slice (4 lanes/rxn), fused vfin write. NO atomics ----
__global__ __launch_bounds__(256) void k_rscale(
    const int* __restrict__ off, const int2* __restrict__ edges8,
    const float* __restrict__ met_scale, const float* __restrict__ v_pre,
    float* __restrict__ vfin) {
  __shared__ int soff[MV_RPB + 1];
  int tid = threadIdx.x, lane = tid & 63, w = tid >> 6;
  int B0 = blockIdx.x * MV_RPB;
  for (int i = tid; i <= MV_RPB; i += 256) {
    int r = B0 + i;
    soff[i] = off[r > N_RXN ? N_RXN : r];
  }
  __syncthreads();

  int rloc = w * 16 + (lane >> 2);
  int o0 = soff[rloc], o1 = soff[rloc + 1];
  float sc = 1.0f;
  for (int c = o0 + (lane & 3); c < o1; c += 4) {
    sc = fminf(sc, met_scale[edges8[c].x]);
  }
  sc = fminf(sc, __shfl_xor(sc, 1, 64));
  sc = fminf(sc, __shfl_xor(sc, 2, 64));
  if ((lane & 3) == 0) {
    int r = B0 + rloc;
    if (r < N_RXN) vfin[r] = v_pre[r] * sc;
  }
}

__global__ void k_contrib(const int* __restrict__ met_all, const int* __restrict__ rxn_all,
                          const float* __restrict__ sto_all, const float* __restrict__ vfin,
                          float* __restrict__ dxdt, float* __restrict__ dxdt_part,
                          int use_part) {
  int t = blockIdx.x * blockDim.x + threadIdx.x;
  if (t < E_ALL / 4) {
    v4i me = __builtin_nontemporal_load((const v4i*)met_all + t);
    v4i re = __builtin_nontemporal_load((const v4i*)rxn_all + t);
    v4f se = __builtin_nontemporal_load((const v4f*)sto_all + t);
    if (use_part) {
      float* dp = dxdt_part + (size_t)xcc_id() * N_MET;
      atomic_add_l2f(&dp[me.x], se.x * vfin[re.x]);
      atomic_add_l2f(&dp[me.y], se.y * vfin[re.y]);
      atomic_add_l2f(&dp[me.z], se.z * vfin[re.z]);
      atomic_add_l2f(&dp[me.w], se.w * vfin[re.w]);
    } else {
      atomic_add_f32(&dxdt[me.x], se.x * vfin[re.x]);
      atomic_add_f32(&dxdt[me.y], se.y * vfin[re.y]);
      atomic_add_f32(&dxdt[me.z], se.z * vfin[re.z]);
      atomic_add_f32(&dxdt[me.w], se.w * vfin[re.w]);
    }
  }
}

__global__ void k_dxred(const float* __restrict__ dxdt_part, float* __restrict__ dxdt) {
  int m = blockIdx.x * blockDim.x + threadIdx.x;
  if (m < N_MET) {
    float s = 0.f;
    #pragma unroll
    for (int xd = 0; xd < NXCD; ++xd) s += dxdt_part[(size_t)xd * N_MET + m];
    dxdt[m] = s;
  }
}

extern "C" void kernel_launch(void* const* d_in, const int* in_sizes, int n_in,
                              void* d_out, int out_size, void* d_ws, size_t ws_size,
                              hipStream_t stream) {
  const float* x       = (const float*)d_in[0];
  const int*   met_sub = (const int*)d_in[1];
  const int*   rxn_sub = (const int*)d_in[2];
  const float* sto_sub = (const float*)d_in[3];
  const int*   met_all = (const int*)d_in[4];
  const int*   rxn_all = (const int*)d_in[5];
  const float* sto_all = (const float*)d_in[6];
  const float* W1    = (const float*)d_in[7];
  const float* b1    = (const float*)d_in[8];
  const float* W2    = (const float*)d_in[9];
  const float* b2    = (const float*)d_in[10];
  const float* W3    = (const float*)d_in[11];
  const float* b3    = (const float*)d_in[12];
  const float* W4    = (const float*)d_in[13];
  const float* b4    = (const float*)d_in[14];
  const float* log_k = (const float*)d_in[15];
  float* dxdt = (float*)d_out;

  char* ws = (char*)d_ws;
  size_t p = 0;
  auto alloc = [&](size_t bytes) -> void* {
    void* r = (void*)(ws + p);
    p += (bytes + 255) & ~(size_t)255;
    return r;
  };
  int*    counts    = (int*)alloc(sizeof(int) * N_RXN);
  int*    off       = (int*)alloc(sizeof(int) * (N_RXN + 1));
  int*    cursor    = (int*)alloc(sizeof(int) * N_RXN);
  int*    bsums     = (int*)alloc(sizeof(int) * 1024);
  uint4*  wfh       = (uint4*)alloc(sizeof(uint4) * 512);
  uint4*  wfl       = (uint4*)alloc(sizeof(uint4) * 512);
  float*  b2w3      = (float*)alloc(sizeof(float) * 64);
  float*  v_pre     = (float*)alloc(sizeof(float) * N_RXN);
  float*  vfin      = (float*)alloc(sizeof(float) * N_RXN);
  float*  conc      = (float*)alloc(sizeof(float) * N_MET);
  float*  total     = (float*)alloc(sizeof(float) * N_MET);
  float*  met_scale = (float*)alloc(sizeof(float) * N_MET);
  int2*   edges8    = (int2*)alloc(sizeof(int2) * E_SUB);   // {m, sto} CSR-ordered
  unsigned short* Thi = (unsigned short*)alloc(sizeof(unsigned short) * (size_t)N_RXN_PAD * 64);
  size_t tlo_bytes = sizeof(unsigned short) * (size_t)N_RXN_PAD * 64;
  int use_lo = (p + tlo_bytes <= ws_size) ? 1 : 0;
  unsigned short* Tlo = use_lo ? (unsigned short*)alloc(tlo_bytes) : Thi;
  // per-XCD partial buffers (32 MB); fall back to agent atomics if ws is tight
  size_t part_bytes = sizeof(int) * (size_t)NXCD * N_RXN +
                      sizeof(float) * (size_t)NXCD * N_MET * 2 + 1024;
  int use_part = (p + part_bytes <= ws_size) ? 1 : 0;
  int*   counts_part = use_part ? (int*)alloc(sizeof(int) * (size_t)NXCD * N_RXN) : counts;
  float* total_part  = use_part ? (float*)alloc(sizeof(float) * (size_t)NXCD * N_MET) : total;
  float* dxdt_part   = use_part ? (float*)alloc(sizeof(float) * (size_t)NXCD * N_MET) : dxdt;
  (void)in_sizes; (void)n_in; (void)out_size;

  if (use_part) {
    hipMemsetAsync(counts_part, 0, sizeof(int) * (size_t)NXCD * N_RXN, stream);
    hipMemsetAsync(total_part, 0, sizeof(float) * (size_t)NXCD * N_MET, stream);
    hipMemsetAsync(dxdt_part, 0, sizeof(float) * (size_t)NXCD * N_MET, stream);
  } else {
    hipMemsetAsync(counts, 0, sizeof(int) * N_RXN, stream);
    hipMemsetAsync(total, 0, sizeof(float) * N_MET, stream);
    hipMemsetAsync(dxdt, 0, sizeof(float) * N_MET, stream);
  }

  k_pre<<<2, 256, 0, stream>>>(W2, W3, b2, wfh, wfl, b2w3);
  k_hist<<<(E_SUB / 4 + 255) / 256, 256, 0, stream>>>(rxn_sub, x, counts, counts_part,
                                                      conc, use_part);
  if (use_part)
    k_sumc<<<(N_RXN + 255) / 256, 256, 0, stream>>>(counts_part, counts);
  k_scan1<<<SCAN_NB, SCAN_T, 0, stream>>>(counts, bsums);
  k_scan2<<<1, SCAN_T, 0, stream>>>(bsums);
  k_scan3<<<SCAN_NB, SCAN_T, 0, stream>>>(counts, bsums, off, cursor);
  k_scatter<<<(E_SUB + 255) / 256, 256, 0, stream>>>(rxn_sub, met_sub, sto_sub,
                                                     cursor, edges8);
  k_edge<<<(N_RXN + RXN_PER_BLK - 1) / RXN_PER_BLK, THREADS, 0, stream>>>(
      off, edges8, conc, W1, b1, Thi, Tlo, use_lo);
  k_mv<<<(N_RXN + MV_RPB - 1) / MV_RPB, 256, 0, stream>>>(
      off, edges8, Thi, Tlo, wfh, wfl, b2w3, b3, W4, b4, log_k, use_lo, use_part,
      v_pre, total, total_part);
  k_scale<<<(N_MET + 255) / 256, 256, 0, stream>>>(total, total_part, conc, met_scale,
                                                   use_part);
  k_rscale<<<(N_RXN + MV_RPB - 1) / MV_RPB, 256, 0, stream>>>(
      off, edges8, met_scale, v_pre, vfin);
  k_contrib<<<(E_ALL / 4 + 255) / 256, 256, 0, stream>>>(met_all, rxn_all, sto_all, vfin,
                                                         dxdt, dxdt_part, use_part);
  if (use_part)
    k_dxred<<<(N_MET + 255) / 256, 256, 0, stream>>>(dxdt_part, dxdt);
}

// Round 9
// 712.457 us; speedup vs baseline: 1.0865x; 1.0865x over previous
//
#include <hip/hip_runtime.h>

#define N_MET 250000
#define N_RXN 500000
#define N_RXN_PAD 500032   // padded rows for T so MFMA tail tiles stay in-bounds
#define E_SUB 2000000
#define E_ALL 4000000
#define DT 0.01f

#define RXN_PER_BLK 256
#define THREADS 256
#define EDGE_CAP 1536   // Poisson(1024) +16 sigma; global fallback below

#define MV_RPB 64       // k_mv reactions per block (4 waves x 16)

// binned scatter-reduce for dxdt
#define BINSZ 1024
#define NBINS ((N_MET + BINSZ - 1) / BINSZ)            // 245
#define PART_EPB 4096
#define PART_NBLK ((E_ALL + PART_EPB - 1) / PART_EPB)  // 977

#define SCAN_T 256
#define SCAN_V 8
#define SCAN_CHUNK (SCAN_T * SCAN_V)
#define SCAN_NB ((N_RXN + SCAN_CHUNK - 1) / SCAN_CHUNK)
static_assert(SCAN_NB <= SCAN_T, "scan2 single block must cover all block sums");

typedef int v4i __attribute__((ext_vector_type(4)));
typedef float v4f __attribute__((ext_vector_type(4)));
typedef short bf16x8 __attribute__((ext_vector_type(8)));
typedef float f32x4 __attribute__((ext_vector_type(4)));

static __device__ __forceinline__ float fast_tanh(float x) {
  float e = __expf(x + x);
  return 1.0f - __fdividef(2.0f, e + 1.0f);
}

static __device__ __forceinline__ void atomic_add_f32(float* p, float v) {
  __hip_atomic_fetch_add(p, v, __ATOMIC_RELAXED, __HIP_MEMORY_SCOPE_AGENT);
}

static __device__ __forceinline__ int bcast_i(int v, int lane) {
  return __builtin_amdgcn_readlane(v, lane);
}

static __device__ __forceinline__ unsigned short bf16_rn(float f) {
  unsigned u = __float_as_uint(f);
  unsigned r = u + 0x7FFFu + ((u >> 16) & 1u);
  return (unsigned short)(r >> 16);
}

// ---- precompute MFMA B-fragments of W23 = W2@W3 (bf16 hi/lo) and b2@W3 ----
__global__ void k_pre(const float* __restrict__ W2, const float* __restrict__ W3,
                      const float* __restrict__ b2,
                      uint4* __restrict__ wfh, uint4* __restrict__ wfl,
                      float* __restrict__ b2w3) {
  int tid = blockIdx.x * blockDim.x + threadIdx.x;
  if (tid < 512) {
    int lane = tid & 63, jt = (tid >> 6) & 3, ks = tid >> 8;
    int jj = jt * 16 + (lane & 15);
    unsigned short h[8], l[8];
    #pragma unroll
    for (int t = 0; t < 8; ++t) {
      int kk = ks * 32 + (lane >> 4) * 8 + t;
      float w = 0.f;
      #pragma unroll
      for (int m = 0; m < 32; ++m) w = fmaf(W2[kk * 32 + m], W3[m * 64 + jj], w);
      h[t] = bf16_rn(w);
      float hf = __uint_as_float(((unsigned)h[t]) << 16);
      l[t] = bf16_rn(w - hf);
    }
    uint4 H, L;
    H.x = (unsigned)h[0] | ((unsigned)h[1] << 16);
    H.y = (unsigned)h[2] | ((unsigned)h[3] << 16);
    H.z = (unsigned)h[4] | ((unsigned)h[5] << 16);
    H.w = (unsigned)h[6] | ((unsigned)h[7] << 16);
    L.x = (unsigned)l[0] | ((unsigned)l[1] << 16);
    L.y = (unsigned)l[2] | ((unsigned)l[3] << 16);
    L.z = (unsigned)l[4] | ((unsigned)l[5] << 16);
    L.w = (unsigned)l[6] | ((unsigned)l[7] << 16);
    int idx = (ks * 4 + jt) * 64 + lane;
    wfh[idx] = H; wfl[idx] = L;
  }
  if (tid < 64) {
    float t = 0.f;
    #pragma unroll
    for (int m = 0; m < 32; ++m) t = fmaf(b2[m], W3[m * 64 + tid], t);
    b2w3[tid] = t;
  }
}

// ---- histogram + dense conc extraction ----
__global__ void k_hist(const int* __restrict__ rxn_sub, const float* __restrict__ x,
                       int* __restrict__ counts, float* __restrict__ conc) {
  int t = blockIdx.x * blockDim.x + threadIdx.x;
  if (t < E_SUB / 4) {
    v4i r = __builtin_nontemporal_load((const v4i*)rxn_sub + t);
    atomicAdd(&counts[r.x], 1);
    atomicAdd(&counts[r.y], 1);
    atomicAdd(&counts[r.z], 1);
    atomicAdd(&counts[r.w], 1);
  }
  if (t < N_MET) conc[t] = __builtin_nontemporal_load(x + t * 8 + 3);
}

__global__ void k_scan1(const int* __restrict__ counts, int* __restrict__ bsums) {
  __shared__ int ss[SCAN_T];
  int b = blockIdx.x, t = threadIdx.x;
  int base = b * SCAN_CHUNK + t * SCAN_V;
  int s = 0;
  #pragma unroll
  for (int k = 0; k < SCAN_V; ++k) { int i = base + k; if (i < N_RXN) s += counts[i]; }
  ss[t] = s; __syncthreads();
  for (int d = SCAN_T / 2; d > 0; d >>= 1) {
    if (t < d) ss[t] += ss[t + d];
    __syncthreads();
  }
  if (t == 0) bsums[b] = ss[0];
}

__global__ void k_scan2(int* __restrict__ bsums) {
  __shared__ int ss[SCAN_T];
  int t = threadIdx.x;
  int v = (t < SCAN_NB) ? bsums[t] : 0;
  ss[t] = v; __syncthreads();
  for (int d = 1; d < SCAN_T; d <<= 1) {
    int a = (t >= d) ? ss[t - d] : 0;
    __syncthreads();
    ss[t] += a;
    __syncthreads();
  }
  if (t < SCAN_NB) bsums[t] = ss[t] - v;  // exclusive
}

__global__ void k_scan3(const int* __restrict__ counts, const int* __restrict__ bsums,
                        int* __restrict__ off, int* __restrict__ cursor) {
  __shared__ int ss[SCAN_T];
  int b = blockIdx.x, t = threadIdx.x;
  int base = b * SCAN_CHUNK + t * SCAN_V;
  int v[SCAN_V];
  int s = 0;
  #pragma unroll
  for (int k = 0; k < SCAN_V; ++k) { int i = base + k; v[k] = (i < N_RXN) ? counts[i] : 0; s += v[k]; }
  ss[t] = s; __syncthreads();
  for (int d = 1; d < SCAN_T; d <<= 1) {
    int a = (t >= d) ? ss[t - d] : 0;
    __syncthreads();
    ss[t] += a;
    __syncthreads();
  }
  int run = bsums[b] + ss[t] - s;
  #pragma unroll
  for (int k = 0; k < SCAN_V; ++k) {
    int i = base + k;
    if (i < N_RXN) { off[i] = run; cursor[i] = run; }
    run += v[k];
  }
  if (b == 0 && t == 0) off[N_RXN] = E_SUB;
}

// ---- scatter into CSR order: 8B record per edge {m, bitcast(sto)} ----
__global__ void k_scatter(const int* __restrict__ rxn_sub, const int* __restrict__ met_sub,
                          const float* __restrict__ sto_sub,
                          int* __restrict__ cursor, int2* __restrict__ edges8) {
  int e = blockIdx.x * blockDim.x + threadIdx.x;
  if (e < E_SUB) {
    int r = __builtin_nontemporal_load(rxn_sub + e);
    int m = __builtin_nontemporal_load(met_sub + e);
    float st = __builtin_nontemporal_load(sto_sub + e);
    int pos = atomicAdd(&cursor[r], 1);
    int2 rec; rec.x = m; rec.y = __float_as_int(st);
    edges8[pos] = rec;
  }
}

// ---- k_edge: wave-per-reaction edge tanh-sum; T -> bf16 hi/lo, row-major [r][64] ----
static __device__ __forceinline__ float edge_sum_lds(int o0, int o1, int estart,
                                                     const float2* ep,
                                                     float w1x, float w1y, float b1j) {
  float T0 = 0.f, T1 = 0.f;
  int c = o0;
  for (; c + 1 < o1; c += 2) {
    float2 e0 = ep[c - estart];
    float2 e1 = ep[c + 1 - estart];
    T0 += fast_tanh(fmaf(e0.x, w1x, fmaf(e0.y, w1y, b1j)));
    T1 += fast_tanh(fmaf(e1.x, w1x, fmaf(e1.y, w1y, b1j)));
  }
  if (c < o1) {
    float2 e0 = ep[c - estart];
    T0 += fast_tanh(fmaf(e0.x, w1x, fmaf(e0.y, w1y, b1j)));
  }
  return T0 + T1;
}

static __device__ __forceinline__ float edge_sum_glob(int o0, int o1,
                                                      const int2* edges8,
                                                      const float* conc,
                                                      float w1x, float w1y, float b1j) {
  float T = 0.f;
  for (int c = o0; c < o1; ++c) {
    int2 rec = edges8[c];
    float cc = conc[rec.x];
    T += fast_tanh(fmaf(cc, w1x, fmaf(__int_as_float(rec.y), w1y, b1j)));
  }
  return T;
}

__global__ __launch_bounds__(THREADS) void k_edge(
    const int* __restrict__ off, const int2* __restrict__ edges8,
    const float* __restrict__ conc,
    const float* __restrict__ W1, const float* __restrict__ b1,
    unsigned short* __restrict__ Thi, unsigned short* __restrict__ Tlo, int use_lo) {
  __shared__ int off_s[RXN_PER_BLK + 1];
  __shared__ float2 se[EDGE_CAP];

  int tid = threadIdx.x;
  int lane = tid & 63;
  int wv = tid >> 6;
  int R0 = blockIdx.x * RXN_PER_BLK;

  for (int i = tid; i <= RXN_PER_BLK; i += THREADS) {
    int r = R0 + i;
    off_s[i] = off[r > N_RXN ? N_RXN : r];
  }
  __syncthreads();
  int estart = off_s[0];
  int nE = off_s[RXN_PER_BLK] - estart;
  bool fits = (nE <= EDGE_CAP);
  if (fits) {
    for (int i = tid; i < nE; i += THREADS) {
      int2 rec = edges8[estart + i];
      se[i] = make_float2(conc[rec.x], __int_as_float(rec.y));
    }
  }

  float w1x = W1[lane], w1y = W1[64 + lane], b1j = b1[lane];

  int rbase = R0 + wv * 64;
  int o0l = off_s[wv * 64 + lane];
  int o1l = off_s[wv * 64 + lane + 1];

  __syncthreads();

  #pragma clang loop unroll(disable)
  for (int i = 0; i < 64; ++i) {
    int r = rbase + i;
    if (r >= N_RXN) break;  // uniform
    int o0 = bcast_i(o0l, i), o1 = bcast_i(o1l, i);
    float T = fits ? edge_sum_lds(o0, o1, estart, se, w1x, w1y, b1j)
                   : edge_sum_glob(o0, o1, edges8, conc, w1x, w1y, b1j);
    unsigned short hi = bf16_rn(T);
    Thi[r * 64 + lane] = hi;
    if (use_lo) {
      float hf = __uint_as_float(((unsigned)hi) << 16);
      Tlo[r * 64 + lane] = bf16_rn(T - hf);
    }
  }
}

// ---- k_mv: U = T @ W23 via MFMA (bf16 hi/lo), fused epilogue + consumption ----
__global__ __launch_bounds__(256) void k_mv(
    const int* __restrict__ off, const int2* __restrict__ edges8,
    const unsigned short* __restrict__ Thi, const unsigned short* __restrict__ Tlo,
    const uint4* __restrict__ wfh, const uint4* __restrict__ wfl,
    const float* __restrict__ b2w3, const float* __restrict__ b3,
    const float* __restrict__ W4, const float* __restrict__ b4,
    const float* __restrict__ log_k, int use_lo,
    float* __restrict__ v_pre, float* __restrict__ total) {
  __shared__ int soff[MV_RPB + 1];
  int tid = threadIdx.x, lane = tid & 63, w = tid >> 6;
  int B0 = blockIdx.x * MV_RPB;
  for (int i = tid; i <= MV_RPB; i += 256) {
    int r = B0 + i;
    soff[i] = off[r > N_RXN ? N_RXN : r];
  }
  __syncthreads();

  int R0 = B0 + w * 16;
  int col = lane & 15, rowg = lane >> 4;

  bf16x8 ah[2], al[2];
  {
    int rowelem = (R0 + col) * 64 + rowg * 8;
    const uint4* ph = (const uint4*)Thi;
    ah[0] = __builtin_bit_cast(bf16x8, ph[rowelem >> 3]);
    ah[1] = __builtin_bit_cast(bf16x8, ph[(rowelem + 32) >> 3]);
    if (use_lo) {
      const uint4* pl = (const uint4*)Tlo;
      al[0] = __builtin_bit_cast(bf16x8, pl[rowelem >> 3]);
      al[1] = __builtin_bit_cast(bf16x8, pl[(rowelem + 32) >> 3]);
    }
  }

  f32x4 acc[4];
  #pragma unroll
  for (int jt = 0; jt < 4; ++jt) acc[jt] = (f32x4){0.f, 0.f, 0.f, 0.f};

  #pragma unroll
  for (int jt = 0; jt < 4; ++jt) {
    #pragma unroll
    for (int ks = 0; ks < 2; ++ks) {
      int bidx = (ks * 4 + jt) * 64 + lane;
      bf16x8 bh = __builtin_bit_cast(bf16x8, wfh[bidx]);
      acc[jt] = __builtin_amdgcn_mfma_f32_16x16x32_bf16(ah[ks], bh, acc[jt], 0, 0, 0);
      if (use_lo) {
        bf16x8 bl = __builtin_bit_cast(bf16x8, wfl[bidx]);
        acc[jt] = __builtin_amdgcn_mfma_f32_16x16x32_bf16(ah[ks], bl, acc[jt], 0, 0, 0);
        acc[jt] = __builtin_amdgcn_mfma_f32_16x16x32_bf16(al[ks], bh, acc[jt], 0, 0, 0);
      }
    }
  }

  float w4c[4], bwc[4], b3c[4];
  #pragma unroll
  for (int jt = 0; jt < 4; ++jt) {
    int jj = jt * 16 + col;
    w4c[jt] = W4[jj]; bwc[jt] = b2w3[jj]; b3c[jt] = b3[jj];
  }
  float b40 = b4[0];

  float nq[4];
  #pragma unroll
  for (int q = 0; q < 4; ++q) {
    int idx = w * 16 + rowg * 4 + q;
    nq[q] = (float)(soff[idx + 1] - soff[idx]);
  }

  float vq[4];
  #pragma unroll
  for (int q = 0; q < 4; ++q) {
    float s = 0.f;
    #pragma unroll
    for (int jt = 0; jt < 4; ++jt) {
      float u = acc[jt][q] + nq[q] * bwc[jt] + b3c[jt];
      s += fast_tanh(u) * w4c[jt];
    }
    s += __shfl_xor(s, 1, 64);
    s += __shfl_xor(s, 2, 64);
    s += __shfl_xor(s, 4, 64);
    s += __shfl_xor(s, 8, 64);
    int r = R0 + rowg * 4 + q;
    float lk = (r < N_RXN) ? log_k[r] : 0.f;
    float racc = s + b40;
    float k10 = __expf(lk * 2.3025850929940457f);
    float sp = (racc > 15.f) ? racc : __logf(1.f + __expf(racc));
    vq[q] = k10 * sp;
  }

  if (col == 0) {
    #pragma unroll
    for (int q = 0; q < 4; ++q) {
      int r = R0 + rowg * 4 + q;
      if (r < N_RXN) v_pre[r] = vq[q];
    }
  }

  // consumption: 4 lanes per reaction walk its CSR slice
  int rloc = lane >> 2;
  float vdt = vq[(lane >> 2) & 3] * DT;
  int o0 = soff[w * 16 + rloc], o1 = soff[w * 16 + rloc + 1];
  for (int c = o0 + (lane & 3); c < o1; c += 4) {
    int2 e = edges8[c];
    atomic_add_f32(&total[e.x], __int_as_float(e.y) * vdt);
  }
}

__global__ void k_scale(const float* __restrict__ total, const float* __restrict__ conc,
                        float* __restrict__ met_scale) {
  int m = blockIdx.x * blockDim.x + threadIdx.x;
  if (m < N_MET) {
    float tot = total[m];
    float cc = conc[m];
    met_scale[m] = (tot > 1e-12f) ? fminf(cc / tot, 1.0f) : 1.0f;
  }
}

// ---- k_rscale: per-rxn min over CSR slice (4 lanes/rxn), fused vfin write. NO atomics ----
__global__ __launch_bounds__(256) void k_rscale(
    const int* __restrict__ off, const int2* __restrict__ edges8,
    const float* __restrict__ met_scale, const float* __restrict__ v_pre,
    float* __restrict__ vfin) {
  __shared__ int soff[MV_RPB + 1];
  int tid = threadIdx.x, lane = tid & 63, w = tid >> 6;
  int B0 = blockIdx.x * MV_RPB;
  for (int i = tid; i <= MV_RPB; i += 256) {
    int r = B0 + i;
    soff[i] = off[r > N_RXN ? N_RXN : r];
  }
  __syncthreads();

  int rloc = w * 16 + (lane >> 2);
  int o0 = soff[rloc], o1 = soff[rloc + 1];
  float sc = 1.0f;
  for (int c = o0 + (lane & 3); c < o1; c += 4) {
    sc = fminf(sc, met_scale[edges8[c].x]);
  }
  sc = fminf(sc, __shfl_xor(sc, 1, 64));
  sc = fminf(sc, __shfl_xor(sc, 2, 64));
  if ((lane & 3) == 0) {
    int r = B0 + rloc;
    if (r < N_RXN) vfin[r] = v_pre[r] * sc;
  }
}

// ==== dxdt via binned two-phase scatter-reduce (zero hot-path global atomics) ====

// phase 0: per-block bin histogram of met_all -> blk_cnt[bin][block] (plain writes)
__global__ __launch_bounds__(256) void k_bc(const int* __restrict__ met_all,
                                            int* __restrict__ blk_cnt) {
  __shared__ int cnt[NBINS];
  int b = blockIdx.x, t = threadIdx.x;
  for (int i = t; i < NBINS; i += 256) cnt[i] = 0;
  __syncthreads();
  int base = b * PART_EPB;
  #pragma unroll
  for (int i = 0; i < PART_EPB / 256; ++i) {
    int e = base + i * 256 + t;
    if (e < E_ALL) atomicAdd(&cnt[__builtin_nontemporal_load(met_all + e) >> 10], 1);
  }
  __syncthreads();
  for (int i = t; i < NBINS; i += 256) blk_cnt[i * PART_NBLK + b] = cnt[i];
}

// phase 0b: per-bin exclusive scan across blocks -> blk_pref, bin totals
__global__ __launch_bounds__(256) void k_bscan1(const int* __restrict__ blk_cnt,
                                                int* __restrict__ blk_pref,
                                                int* __restrict__ bin_tot) {
  __shared__ int ss[256];
  int j = blockIdx.x, t = threadIdx.x;
  int carry = 0;
  for (int c = 0; c < PART_NBLK; c += 256) {
    int idx = c + t;
    int v = (idx < PART_NBLK) ? blk_cnt[j * PART_NBLK + idx] : 0;
    ss[t] = v; __syncthreads();
    for (int d = 1; d < 256; d <<= 1) {
      int a = (t >= d) ? ss[t - d] : 0;
      __syncthreads();
      ss[t] += a;
      __syncthreads();
    }
    if (idx < PART_NBLK) blk_pref[j * PART_NBLK + idx] = carry + ss[t] - v;
    carry += ss[255];
    __syncthreads();
  }
  if (t == 0) bin_tot[j] = carry;
}

// phase 0c: exclusive scan of bin totals -> bin_start
__global__ void k_bscan2(const int* __restrict__ bin_tot, int* __restrict__ bin_start) {
  __shared__ int ss[256];
  int t = threadIdx.x;
  int v = (t < NBINS) ? bin_tot[t] : 0;
  ss[t] = v; __syncthreads();
  for (int d = 1; d < 256; d <<= 1) {
    int a = (t >= d) ? ss[t - d] : 0;
    __syncthreads();
    ss[t] += a;
    __syncthreads();
  }
  if (t < NBINS) bin_start[t] = ss[t] - v;
}

// phase 1: partition {m&1023, sto*vfin[r]} into bin segments (LDS cursors, plain stores)
__global__ __launch_bounds__(256) void k_part(
    const int* __restrict__ met_all, const int* __restrict__ rxn_all,
    const float* __restrict__ sto_all, const float* __restrict__ vfin,
    const int* __restrict__ blk_pref, const int* __restrict__ bin_start,
    int2* __restrict__ bins) {
  __shared__ int cur[NBINS];
  int b = blockIdx.x, t = threadIdx.x;
  for (int i = t; i < NBINS; i += 256) cur[i] = bin_start[i] + blk_pref[i * PART_NBLK + b];
  __syncthreads();
  int base = b * PART_EPB;
  #pragma unroll
  for (int i = 0; i < PART_EPB / 256; ++i) {
    int e = base + i * 256 + t;
    if (e < E_ALL) {
      int m = __builtin_nontemporal_load(met_all + e);
      int r = __builtin_nontemporal_load(rxn_all + e);
      float st = __builtin_nontemporal_load(sto_all + e);
      float val = st * vfin[r];
      int pos = atomicAdd(&cur[m >> 10], 1);  // LDS atomic
      int2 rec; rec.x = m & (BINSZ - 1); rec.y = __float_as_int(val);
      bins[pos] = rec;
    }
  }
}

// phase 2: one block per bin, LDS accumulate, dense dxdt write (covers all mets)
__global__ __launch_bounds__(256) void k_bins(const int2* __restrict__ bins,
                                              const int* __restrict__ bin_start,
                                              const int* __restrict__ bin_tot,
                                              float* __restrict__ dxdt) {
  __shared__ float acc[BINSZ];
  int j = blockIdx.x, t = threadIdx.x;
  for (int i = t; i < BINSZ; i += 256) acc[i] = 0.f;
  __syncthreads();
  int s0 = bin_start[j], n = bin_tot[j];
  for (int i = t; i < n; i += 256) {
    int2 rec = bins[s0 + i];
    atomicAdd(&acc[rec.x], __int_as_float(rec.y));  // LDS fp32 atomic
  }
  __syncthreads();
  int m0 = j * BINSZ;
  for (int i = t; i < BINSZ; i += 256) {
    int m = m0 + i;
    if (m < N_MET) dxdt[m] = acc[i];
  }
}

extern "C" void kernel_launch(void* const* d_in, const int* in_sizes, int n_in,
                              void* d_out, int out_size, void* d_ws, size_t ws_size,
                              hipStream_t stream) {
  const float* x       = (const float*)d_in[0];
  const int*   met_sub = (const int*)d_in[1];
  const int*   rxn_sub = (const int*)d_in[2];
  const float* sto_sub = (const float*)d_in[3];
  const int*   met_all = (const int*)d_in[4];
  const int*   rxn_all = (const int*)d_in[5];
  const float* sto_all = (const float*)d_in[6];
  const float* W1    = (const float*)d_in[7];
  const float* b1    = (const float*)d_in[8];
  const float* W2    = (const float*)d_in[9];
  const float* b2    = (const float*)d_in[10];
  const float* W3    = (const float*)d_in[11];
  const float* b3    = (const float*)d_in[12];
  const float* W4    = (const float*)d_in[13];
  const float* b4    = (const float*)d_in[14];
  const float* log_k = (const float*)d_in[15];
  float* dxdt = (float*)d_out;

  char* ws = (char*)d_ws;
  size_t p = 0;
  auto alloc = [&](size_t bytes) -> void* {
    void* r = (void*)(ws + p);
    p += (bytes + 255) & ~(size_t)255;
    return r;
  };
  int*    counts    = (int*)alloc(sizeof(int) * N_RXN);
  int*    off       = (int*)alloc(sizeof(int) * (N_RXN + 1));
  int*    cursor    = (int*)alloc(sizeof(int) * N_RXN);
  int*    bsums     = (int*)alloc(sizeof(int) * 1024);
  uint4*  wfh       = (uint4*)alloc(sizeof(uint4) * 512);
  uint4*  wfl       = (uint4*)alloc(sizeof(uint4) * 512);
  float*  b2w3      = (float*)alloc(sizeof(float) * 64);
  float*  v_pre     = (float*)alloc(sizeof(float) * N_RXN);
  float*  vfin      = (float*)alloc(sizeof(float) * N_RXN);
  float*  conc      = (float*)alloc(sizeof(float) * N_MET);
  float*  total     = (float*)alloc(sizeof(float) * N_MET);
  float*  met_scale = (float*)alloc(sizeof(float) * N_MET);
  int2*   edges8    = (int2*)alloc(sizeof(int2) * E_SUB);   // {m, sto} CSR-ordered
  int2*   bins      = (int2*)alloc(sizeof(int2) * E_ALL);   // binned {m_local, val}
  int*    blk_cnt   = (int*)alloc(sizeof(int) * NBINS * PART_NBLK);
  int*    blk_pref  = (int*)alloc(sizeof(int) * NBINS * PART_NBLK);
  int*    bin_tot   = (int*)alloc(sizeof(int) * 256);
  int*    bin_start = (int*)alloc(sizeof(int) * 256);
  unsigned short* Thi = (unsigned short*)alloc(sizeof(unsigned short) * (size_t)N_RXN_PAD * 64);
  size_t tlo_bytes = sizeof(unsigned short) * (size_t)N_RXN_PAD * 64;
  int use_lo = (p + tlo_bytes <= ws_size) ? 1 : 0;
  unsigned short* Tlo = use_lo ? (unsigned short*)alloc(tlo_bytes) : Thi;
  (void)in_sizes; (void)n_in; (void)out_size;

  hipMemsetAsync(counts, 0, sizeof(int) * N_RXN, stream);
  hipMemsetAsync(total, 0, sizeof(float) * N_MET, stream);
  // dxdt fully overwritten by k_bins -- no memset needed

  k_pre<<<2, 256, 0, stream>>>(W2, W3, b2, wfh, wfl, b2w3);
  k_hist<<<(E_SUB / 4 + 255) / 256, 256, 0, stream>>>(rxn_sub, x, counts, conc);
  k_scan1<<<SCAN_NB, SCAN_T, 0, stream>>>(counts, bsums);
  k_scan2<<<1, SCAN_T, 0, stream>>>(bsums);
  k_scan3<<<SCAN_NB, SCAN_T, 0, stream>>>(counts, bsums, off, cursor);
  k_scatter<<<(E_SUB + 255) / 256, 256, 0, stream>>>(rxn_sub, met_sub, sto_sub,
                                                     cursor, edges8);
  // bin-prep for dxdt can run any time before k_part
  k_bc<<<PART_NBLK, 256, 0, stream>>>(met_all, blk_cnt);
  k_bscan1<<<NBINS, 256, 0, stream>>>(blk_cnt, blk_pref, bin_tot);
  k_bscan2<<<1, 256, 0, stream>>>(bin_tot, bin_start);
  k_edge<<<(N_RXN + RXN_PER_BLK - 1) / RXN_PER_BLK, THREADS, 0, stream>>>(
      off, edges8, conc, W1, b1, Thi, Tlo, use_lo);
  k_mv<<<(N_RXN + MV_RPB - 1) / MV_RPB, 256, 0, stream>>>(
      off, edges8, Thi, Tlo, wfh, wfl, b2w3, b3, W4, b4, log_k, use_lo, v_pre, total);
  k_scale<<<(N_MET + 255) / 256, 256, 0, stream>>>(total, conc, met_scale);
  k_rscale<<<(N_RXN + MV_RPB - 1) / MV_RPB, 256, 0, stream>>>(
      off, edges8, met_scale, v_pre, vfin);
  k_part<<<PART_NBLK, 256, 0, stream>>>(met_all, rxn_all, sto_all, vfin,
                                        blk_pref, bin_start, bins);
  k_bins<<<NBINS, 256, 0, stream>>>(bins, bin_start, bin_tot, dxdt);
}

// Round 10
// 597.622 us; speedup vs baseline: 1.2953x; 1.1922x over previous
//
#include <hip/hip_runtime.h>

#define N_MET 250000
#define N_RXN 500000
#define N_RXN_PAD 500032   // padded rows for T so MFMA tail tiles stay in-bounds
#define E_SUB 2000000
#define E_ALL 4000000
#define DT 0.01f

#define RXN_PER_BLK 256
#define THREADS 256
#define EDGE_CAP 1536   // k_edge LDS staging cap; global fallback below

#define MV_RPB 64       // k_mv reactions per block (4 waves x 16)

// ---- binning geometry ----
// met bins (dxdt + total): 1024 mets/bin
#define BINSZ 1024
#define NBINS ((N_MET + BINSZ - 1) / BINSZ)                 // 245
#define PART_EPB 4096
#define PART_NBLK ((E_ALL + PART_EPB - 1) / PART_EPB)       // 977
#define SPART_NBLK ((E_SUB + PART_EPB - 1) / PART_EPB)      // 489
// rxn bins (CSR counting sort): 1024 rxns/bin
#define RBINSZ 1024
#define RNBINS ((N_RXN + RBINSZ - 1) / RBINSZ)              // 489
#define RPART_NBLK ((E_SUB + PART_EPB - 1) / PART_EPB)      // 489
#define RBIN_CAP 6144   // Poisson(4096) + ~30 sigma; global fallback below

typedef int v4i __attribute__((ext_vector_type(4)));
typedef float v4f __attribute__((ext_vector_type(4)));
typedef short bf16x8 __attribute__((ext_vector_type(8)));
typedef float f32x4 __attribute__((ext_vector_type(4)));

static __device__ __forceinline__ float fast_tanh(float x) {
  float e = __expf(x + x);
  return 1.0f - __fdividef(2.0f, e + 1.0f);
}

static __device__ __forceinline__ int bcast_i(int v, int lane) {
  return __builtin_amdgcn_readlane(v, lane);
}

static __device__ __forceinline__ unsigned short bf16_rn(float f) {
  unsigned u = __float_as_uint(f);
  unsigned r = u + 0x7FFFu + ((u >> 16) & 1u);
  return (unsigned short)(r >> 16);
}

// ---- precompute MFMA B-fragments of W23 = W2@W3 (bf16 hi/lo) and b2@W3 ----
__global__ void k_pre(const float* __restrict__ W2, const float* __restrict__ W3,
                      const float* __restrict__ b2,
                      uint4* __restrict__ wfh, uint4* __restrict__ wfl,
                      float* __restrict__ b2w3) {
  int tid = blockIdx.x * blockDim.x + threadIdx.x;
  if (tid < 512) {
    int lane = tid & 63, jt = (tid >> 6) & 3, ks = tid >> 8;
    int jj = jt * 16 + (lane & 15);
    unsigned short h[8], l[8];
    #pragma unroll
    for (int t = 0; t < 8; ++t) {
      int kk = ks * 32 + (lane >> 4) * 8 + t;
      float w = 0.f;
      #pragma unroll
      for (int m = 0; m < 32; ++m) w = fmaf(W2[kk * 32 + m], W3[m * 64 + jj], w);
      h[t] = bf16_rn(w);
      float hf = __uint_as_float(((unsigned)h[t]) << 16);
      l[t] = bf16_rn(w - hf);
    }
    uint4 H, L;
    H.x = (unsigned)h[0] | ((unsigned)h[1] << 16);
    H.y = (unsigned)h[2] | ((unsigned)h[3] << 16);
    H.z = (unsigned)h[4] | ((unsigned)h[5] << 16);
    H.w = (unsigned)h[6] | ((unsigned)h[7] << 16);
    L.x = (unsigned)l[0] | ((unsigned)l[1] << 16);
    L.y = (unsigned)l[2] | ((unsigned)l[3] << 16);
    L.z = (unsigned)l[4] | ((unsigned)l[5] << 16);
    L.w = (unsigned)l[6] | ((unsigned)l[7] << 16);
    int idx = (ks * 4 + jt) * 64 + lane;
    wfh[idx] = H; wfl[idx] = L;
  }
  if (tid < 64) {
    float t = 0.f;
    #pragma unroll
    for (int m = 0; m < 32; ++m) t = fmaf(b2[m], W3[m * 64 + tid], t);
    b2w3[tid] = t;
  }
}

// ---- dense conc extraction ----
__global__ void k_conc(const float* __restrict__ x, float* __restrict__ conc) {
  int m = blockIdx.x * blockDim.x + threadIdx.x;
  if (m < N_MET) conc[m] = __builtin_nontemporal_load(x + m * 8 + 3);
}

// ==== generic bin-count / scan kernels (LDS histograms, zero global atomics) ====

// per-block histogram of key>>10 -> blk_cnt[bin][block]
template <int NB>
static __device__ __forceinline__ void bc_body(const int* __restrict__ keys, int nkeys,
                                               int* __restrict__ blk_cnt, int nblk) {
  __shared__ int cnt[NB];
  int b = blockIdx.x, t = threadIdx.x;
  for (int i = t; i < NB; i += 256) cnt[i] = 0;
  __syncthreads();
  int base = b * PART_EPB;
  #pragma unroll
  for (int i = 0; i < PART_EPB / 256; ++i) {
    int e = base + i * 256 + t;
    if (e < nkeys) atomicAdd(&cnt[__builtin_nontemporal_load(keys + e) >> 10], 1);
  }
  __syncthreads();
  for (int i = t; i < NB; i += 256) blk_cnt[i * nblk + b] = cnt[i];
}

__global__ __launch_bounds__(256) void k_bc_all(const int* __restrict__ met_all,
                                                int* __restrict__ blk_cnt) {
  bc_body<NBINS>(met_all, E_ALL, blk_cnt, PART_NBLK);
}
__global__ __launch_bounds__(256) void k_bc_sub(const int* __restrict__ met_sub,
                                                int* __restrict__ blk_cnt) {
  bc_body<NBINS>(met_sub, E_SUB, blk_cnt, SPART_NBLK);
}
__global__ __launch_bounds__(256) void k_rbc(const int* __restrict__ rxn_sub,
                                             int* __restrict__ blk_cnt) {
  bc_body<RNBINS>(rxn_sub, E_SUB, blk_cnt, RPART_NBLK);
}

// per-bin exclusive scan across blocks -> blk_pref, bin totals (grid = nbins)
__global__ __launch_bounds__(256) void k_bscan1(const int* __restrict__ blk_cnt,
                                                int* __restrict__ blk_pref,
                                                int* __restrict__ bin_tot, int nblk) {
  __shared__ int ss[256];
  int j = blockIdx.x, t = threadIdx.x;
  int carry = 0;
  for (int c = 0; c < nblk; c += 256) {
    int idx = c + t;
    int v = (idx < nblk) ? blk_cnt[j * nblk + idx] : 0;
    ss[t] = v; __syncthreads();
    for (int d = 1; d < 256; d <<= 1) {
      int a = (t >= d) ? ss[t - d] : 0;
      __syncthreads();
      ss[t] += a;
      __syncthreads();
    }
    if (idx < nblk) blk_pref[j * nblk + idx] = carry + ss[t] - v;
    carry += ss[255];
    __syncthreads();
  }
  if (t == 0) bin_tot[j] = carry;
}

// exclusive scan of bin totals (n <= 512)
__global__ __launch_bounds__(512) void k_bscan2(const int* __restrict__ bin_tot,
                                                int* __restrict__ bin_start, int n) {
  __shared__ int ss[512];
  int t = threadIdx.x;
  int v = (t < n) ? bin_tot[t] : 0;
  ss[t] = v; __syncthreads();
  for (int d = 1; d < 512; d <<= 1) {
    int a = (t >= d) ? ss[t - d] : 0;
    __syncthreads();
    ss[t] += a;
    __syncthreads();
  }
  if (t < n) bin_start[t] = ss[t] - v;
}

// ==== CSR build by counting sort (no global atomics) ====

// phase 1: partition packed {rloc:10|m:18, sto} into rxn-bin runs
__global__ __launch_bounds__(256) void k_rpart(
    const int* __restrict__ rxn_sub, const int* __restrict__ met_sub,
    const float* __restrict__ sto_sub,
    const int* __restrict__ blk_pref, const int* __restrict__ bin_start,
    int2* __restrict__ bins_rxn) {
  __shared__ int cur[RNBINS];
  int b = blockIdx.x, t = threadIdx.x;
  for (int i = t; i < RNBINS; i += 256) cur[i] = bin_start[i] + blk_pref[i * RPART_NBLK + b];
  __syncthreads();
  int base = b * PART_EPB;
  #pragma unroll
  for (int i = 0; i < PART_EPB / 256; ++i) {
    int e = base + i * 256 + t;
    if (e < E_SUB) {
      int r = __builtin_nontemporal_load(rxn_sub + e);
      int m = __builtin_nontemporal_load(met_sub + e);
      float st = __builtin_nontemporal_load(sto_sub + e);
      int pos = atomicAdd(&cur[r >> 10], 1);  // LDS atomic
      int2 rec; rec.x = ((r & (RBINSZ - 1)) << 18) | m; rec.y = __float_as_int(st);
      bins_rxn[pos] = rec;
    }
  }
}

// phase 2: per-bin local sort -> edges8 CSR order + off[]
__global__ __launch_bounds__(256) void k_rbin(
    const int2* __restrict__ bins_rxn, const int* __restrict__ rbin_start,
    const int* __restrict__ rbin_tot, int2* __restrict__ edges8, int* __restrict__ off) {
  __shared__ int2 stage[RBIN_CAP];   // 48 KB
  __shared__ int lcnt[RBINSZ];
  __shared__ int lcur[RBINSZ];
  __shared__ int ss[256];
  int j = blockIdx.x, t = threadIdx.x;
  int base = rbin_start[j], n = rbin_tot[j];
  for (int i = t; i < RBINSZ; i += 256) lcnt[i] = 0;
  __syncthreads();
  bool fits = (n <= RBIN_CAP);
  if (fits) {
    for (int i = t; i < n; i += 256) {
      int2 rec = bins_rxn[base + i];
      stage[i] = rec;
      atomicAdd(&lcnt[((unsigned)rec.x) >> 18], 1);
    }
  } else {
    for (int i = t; i < n; i += 256) {
      int2 rec = bins_rxn[base + i];
      atomicAdd(&lcnt[((unsigned)rec.x) >> 18], 1);
    }
  }
  __syncthreads();
  // exclusive scan of lcnt[1024] (each thread owns 4)
  int s0 = lcnt[4 * t], s1 = lcnt[4 * t + 1], s2 = lcnt[4 * t + 2], s3 = lcnt[4 * t + 3];
  int tsum = s0 + s1 + s2 + s3;
  ss[t] = tsum; __syncthreads();
  for (int d = 1; d < 256; d <<= 1) {
    int a = (t >= d) ? ss[t - d] : 0;
    __syncthreads();
    ss[t] += a;
    __syncthreads();
  }
  int run = ss[t] - tsum;
  lcur[4 * t] = run;
  lcur[4 * t + 1] = run + s0;
  lcur[4 * t + 2] = run + s0 + s1;
  lcur[4 * t + 3] = run + s0 + s1 + s2;
  __syncthreads();
  // CSR offsets for this bin's rxns
  int R0 = j * RBINSZ;
  for (int rl = t; rl < RBINSZ; rl += 256) {
    int r = R0 + rl;
    if (r < N_RXN) off[r] = base + lcur[rl];
  }
  if (j == 0 && t == 0) off[N_RXN] = E_SUB;
  __syncthreads();
  // scatter into CSR order (writes land in this bin's contiguous window)
  if (fits) {
    for (int i = t; i < n; i += 256) {
      int2 rec = stage[i];
      int pos = atomicAdd(&lcur[((unsigned)rec.x) >> 18], 1);
      int2 out; out.x = rec.x & 0x3FFFF; out.y = rec.y;
      edges8[base + pos] = out;
    }
  } else {
    for (int i = t; i < n; i += 256) {
      int2 rec = bins_rxn[base + i];
      int pos = atomicAdd(&lcur[((unsigned)rec.x) >> 18], 1);
      int2 out; out.x = rec.x & 0x3FFFF; out.y = rec.y;
      edges8[base + pos] = out;
    }
  }
}

// ---- k_edge: wave-per-reaction edge tanh-sum; T -> bf16 hi/lo, row-major [r][64] ----
static __device__ __forceinline__ float edge_sum_lds(int o0, int o1, int estart,
                                                     const float2* ep,
                                                     float w1x, float w1y, float b1j) {
  float T0 = 0.f, T1 = 0.f;
  int c = o0;
  for (; c + 1 < o1; c += 2) {
    float2 e0 = ep[c - estart];
    float2 e1 = ep[c + 1 - estart];
    T0 += fast_tanh(fmaf(e0.x, w1x, fmaf(e0.y, w1y, b1j)));
    T1 += fast_tanh(fmaf(e1.x, w1x, fmaf(e1.y, w1y, b1j)));
  }
  if (c < o1) {
    float2 e0 = ep[c - estart];
    T0 += fast_tanh(fmaf(e0.x, w1x, fmaf(e0.y, w1y, b1j)));
  }
  return T0 + T1;
}

static __device__ __forceinline__ float edge_sum_glob(int o0, int o1,
                                                      const int2* edges8,
                                                      const float* conc,
                                                      float w1x, float w1y, float b1j) {
  float T = 0.f;
  for (int c = o0; c < o1; ++c) {
    int2 rec = edges8[c];
    float cc = conc[rec.x];
    T += fast_tanh(fmaf(cc, w1x, fmaf(__int_as_float(rec.y), w1y, b1j)));
  }
  return T;
}

__global__ __launch_bounds__(THREADS) void k_edge(
    const int* __restrict__ off, const int2* __restrict__ edges8,
    const float* __restrict__ conc,
    const float* __restrict__ W1, const float* __restrict__ b1,
    unsigned short* __restrict__ Thi, unsigned short* __restrict__ Tlo, int use_lo) {
  __shared__ int off_s[RXN_PER_BLK + 1];
  __shared__ float2 se[EDGE_CAP];

  int tid = threadIdx.x;
  int lane = tid & 63;
  int wv = tid >> 6;
  int R0 = blockIdx.x * RXN_PER_BLK;

  for (int i = tid; i <= RXN_PER_BLK; i += THREADS) {
    int r = R0 + i;
    off_s[i] = off[r > N_RXN ? N_RXN : r];
  }
  __syncthreads();
  int estart = off_s[0];
  int nE = off_s[RXN_PER_BLK] - estart;
  bool fits = (nE <= EDGE_CAP);
  if (fits) {
    for (int i = tid; i < nE; i += THREADS) {
      int2 rec = edges8[estart + i];
      se[i] = make_float2(conc[rec.x], __int_as_float(rec.y));
    }
  }

  float w1x = W1[lane], w1y = W1[64 + lane], b1j = b1[lane];

  int rbase = R0 + wv * 64;
  int o0l = off_s[wv * 64 + lane];
  int o1l = off_s[wv * 64 + lane + 1];

  __syncthreads();

  #pragma clang loop unroll(disable)
  for (int i = 0; i < 64; ++i) {
    int r = rbase + i;
    if (r >= N_RXN) break;  // uniform
    int o0 = bcast_i(o0l, i), o1 = bcast_i(o1l, i);
    float T = fits ? edge_sum_lds(o0, o1, estart, se, w1x, w1y, b1j)
                   : edge_sum_glob(o0, o1, edges8, conc, w1x, w1y, b1j);
    unsigned short hi = bf16_rn(T);
    Thi[r * 64 + lane] = hi;
    if (use_lo) {
      float hf = __uint_as_float(((unsigned)hi) << 16);
      Tlo[r * 64 + lane] = bf16_rn(T - hf);
    }
  }
}

// ---- k_mv: U = T @ W23 via MFMA (bf16 hi/lo), epilogue only (no atomics) ----
__global__ __launch_bounds__(256) void k_mv(
    const int* __restrict__ off,
    const unsigned short* __restrict__ Thi, const unsigned short* __restrict__ Tlo,
    const uint4* __restrict__ wfh, const uint4* __restrict__ wfl,
    const float* __restrict__ b2w3, const float* __restrict__ b3,
    const float* __restrict__ W4, const float* __restrict__ b4,
    const float* __restrict__ log_k, int use_lo, float* __restrict__ v_pre) {
  __shared__ int soff[MV_RPB + 1];
  int tid = threadIdx.x, lane = tid & 63, w = tid >> 6;
  int B0 = blockIdx.x * MV_RPB;
  for (int i = tid; i <= MV_RPB; i += 256) {
    int r = B0 + i;
    soff[i] = off[r > N_RXN ? N_RXN : r];
  }
  __syncthreads();

  int R0 = B0 + w * 16;
  int col = lane & 15, rowg = lane >> 4;

  bf16x8 ah[2], al[2];
  {
    int rowelem = (R0 + col) * 64 + rowg * 8;
    const uint4* ph = (const uint4*)Thi;
    ah[0] = __builtin_bit_cast(bf16x8, ph[rowelem >> 3]);
    ah[1] = __builtin_bit_cast(bf16x8, ph[(rowelem + 32) >> 3]);
    if (use_lo) {
      const uint4* pl = (const uint4*)Tlo;
      al[0] = __builtin_bit_cast(bf16x8, pl[rowelem >> 3]);
      al[1] = __builtin_bit_cast(bf16x8, pl[(rowelem + 32) >> 3]);
    }
  }

  f32x4 acc[4];
  #pragma unroll
  for (int jt = 0; jt < 4; ++jt) acc[jt] = (f32x4){0.f, 0.f, 0.f, 0.f};

  #pragma unroll
  for (int jt = 0; jt < 4; ++jt) {
    #pragma unroll
    for (int ks = 0; ks < 2; ++ks) {
      int bidx = (ks * 4 + jt) * 64 + lane;
      bf16x8 bh = __builtin_bit_cast(bf16x8, wfh[bidx]);
      acc[jt] = __builtin_amdgcn_mfma_f32_16x16x32_bf16(ah[ks], bh, acc[jt], 0, 0, 0);
      if (use_lo) {
        bf16x8 bl = __builtin_bit_cast(bf16x8, wfl[bidx]);
        acc[jt] = __builtin_amdgcn_mfma_f32_16x16x32_bf16(ah[ks], bl, acc[jt], 0, 0, 0);
        acc[jt] = __builtin_amdgcn_mfma_f32_16x16x32_bf16(al[ks], bh, acc[jt], 0, 0, 0);
      }
    }
  }

  float w4c[4], bwc[4], b3c[4];
  #pragma unroll
  for (int jt = 0; jt < 4; ++jt) {
    int jj = jt * 16 + col;
    w4c[jt] = W4[jj]; bwc[jt] = b2w3[jj]; b3c[jt] = b3[jj];
  }
  float b40 = b4[0];

  float nq[4];
  #pragma unroll
  for (int q = 0; q < 4; ++q) {
    int idx = w * 16 + rowg * 4 + q;
    nq[q] = (float)(soff[idx + 1] - soff[idx]);
  }

  #pragma unroll
  for (int q = 0; q < 4; ++q) {
    float s = 0.f;
    #pragma unroll
    for (int jt = 0; jt < 4; ++jt) {
      float u = acc[jt][q] + nq[q] * bwc[jt] + b3c[jt];
      s += fast_tanh(u) * w4c[jt];
    }
    s += __shfl_xor(s, 1, 64);
    s += __shfl_xor(s, 2, 64);
    s += __shfl_xor(s, 4, 64);
    s += __shfl_xor(s, 8, 64);
    if (col == 0) {
      int r = R0 + rowg * 4 + q;
      float lk = (r < N_RXN) ? log_k[r] : 0.f;
      float racc = s + b40;
      float k10 = __expf(lk * 2.3025850929940457f);
      float sp = (racc > 15.f) ? racc : __logf(1.f + __expf(racc));
      if (r < N_RXN) v_pre[r] = k10 * sp;
    }
  }
}

// ==== consumption totals via binned scatter-reduce, fused met_scale ====

__global__ __launch_bounds__(256) void k_part_sub(
    const int* __restrict__ met_sub, const int* __restrict__ rxn_sub,
    const float* __restrict__ sto_sub, const float* __restrict__ v_pre,
    const int* __restrict__ blk_pref, const int* __restrict__ bin_start,
    int2* __restrict__ bins_sub) {
  __shared__ int cur[NBINS];
  int b = blockIdx.x, t = threadIdx.x;
  for (int i = t; i < NBINS; i += 256) cur[i] = bin_start[i] + blk_pref[i * SPART_NBLK + b];
  __syncthreads();
  int base = b * PART_EPB;
  #pragma unroll
  for (int i = 0; i < PART_EPB / 256; ++i) {
    int e = base + i * 256 + t;
    if (e < E_SUB) {
      int m = __builtin_nontemporal_load(met_sub + e);
      int r = __builtin_nontemporal_load(rxn_sub + e);
      float st = __builtin_nontemporal_load(sto_sub + e);
      float val = st * v_pre[r] * DT;
      int pos = atomicAdd(&cur[m >> 10], 1);  // LDS atomic
      int2 rec; rec.x = m & (BINSZ - 1); rec.y = __float_as_int(val);
      bins_sub[pos] = rec;
    }
  }
}

// accumulate totals per bin + fused met_scale = min(conc/total, 1)
__global__ __launch_bounds__(256) void k_bins_sub(
    const int2* __restrict__ bins_sub, const int* __restrict__ bin_start,
    const int* __restrict__ bin_tot, const float* __restrict__ conc,
    float* __restrict__ met_scale) {
  __shared__ float acc[BINSZ];
  int j = blockIdx.x, t = threadIdx.x;
  for (int i = t; i < BINSZ; i += 256) acc[i] = 0.f;
  __syncthreads();
  int s0 = bin_start[j], n = bin_tot[j];
  for (int i = t; i < n; i += 256) {
    int2 rec = bins_sub[s0 + i];
    atomicAdd(&acc[rec.x], __int_as_float(rec.y));  // LDS fp32 atomic
  }
  __syncthreads();
  int m0 = j * BINSZ;
  for (int i = t; i < BINSZ; i += 256) {
    int m = m0 + i;
    if (m < N_MET) {
      float tot = acc[i];
      met_scale[m] = (tot > 1e-12f) ? fminf(conc[m] / tot, 1.0f) : 1.0f;
    }
  }
}

// ---- k_rscale: per-rxn min over CSR slice (4 lanes/rxn), fused vfin write ----
__global__ __launch_bounds__(256) void k_rscale(
    const int* __restrict__ off, const int2* __restrict__ edges8,
    const float* __restrict__ met_scale, const float* __restrict__ v_pre,
    float* __restrict__ vfin) {
  __shared__ int soff[MV_RPB + 1];
  int tid = threadIdx.x, lane = tid & 63, w = tid >> 6;
  int B0 = blockIdx.x * MV_RPB;
  for (int i = tid; i <= MV_RPB; i += 256) {
    int r = B0 + i;
    soff[i] = off[r > N_RXN ? N_RXN : r];
  }
  __syncthreads();

  int rloc = w * 16 + (lane >> 2);
  int o0 = soff[rloc], o1 = soff[rloc + 1];
  float sc = 1.0f;
  for (int c = o0 + (lane & 3); c < o1; c += 4) {
    sc = fminf(sc, met_scale[edges8[c].x]);
  }
  sc = fminf(sc, __shfl_xor(sc, 1, 64));
  sc = fminf(sc, __shfl_xor(sc, 2, 64));
  if ((lane & 3) == 0) {
    int r = B0 + rloc;
    if (r < N_RXN) vfin[r] = v_pre[r] * sc;
  }
}

// ==== dxdt via binned scatter-reduce ====

__global__ __launch_bounds__(256) void k_part(
    const int* __restrict__ met_all, const int* __restrict__ rxn_all,
    const float* __restrict__ sto_all, const float* __restrict__ vfin,
    const int* __restrict__ blk_pref, const int* __restrict__ bin_start,
    int2* __restrict__ bins) {
  __shared__ int cur[NBINS];
  int b = blockIdx.x, t = threadIdx.x;
  for (int i = t; i < NBINS; i += 256) cur[i] = bin_start[i] + blk_pref[i * PART_NBLK + b];
  __syncthreads();
  int base = b * PART_EPB;
  #pragma unroll
  for (int i = 0; i < PART_EPB / 256; ++i) {
    int e = base + i * 256 + t;
    if (e < E_ALL) {
      int m = __builtin_nontemporal_load(met_all + e);
      int r = __builtin_nontemporal_load(rxn_all + e);
      float st = __builtin_nontemporal_load(sto_all + e);
      float val = st * vfin[r];
      int pos = atomicAdd(&cur[m >> 10], 1);  // LDS atomic
      int2 rec; rec.x = m & (BINSZ - 1); rec.y = __float_as_int(val);
      bins[pos] = rec;
    }
  }
}

__global__ __launch_bounds__(256) void k_bins(const int2* __restrict__ bins,
                                              const int* __restrict__ bin_start,
                                              const int* __restrict__ bin_tot,
                                              float* __restrict__ dxdt) {
  __shared__ float acc[BINSZ];
  int j = blockIdx.x, t = threadIdx.x;
  for (int i = t; i < BINSZ; i += 256) acc[i] = 0.f;
  __syncthreads();
  int s0 = bin_start[j], n = bin_tot[j];
  for (int i = t; i < n; i += 256) {
    int2 rec = bins[s0 + i];
    atomicAdd(&acc[rec.x], __int_as_float(rec.y));  // LDS fp32 atomic
  }
  __syncthreads();
  int m0 = j * BINSZ;
  for (int i = t; i < BINSZ; i += 256) {
    int m = m0 + i;
    if (m < N_MET) dxdt[m] = acc[i];
  }
}

extern "C" void kernel_launch(void* const* d_in, const int* in_sizes, int n_in,
                              void* d_out, int out_size, void* d_ws, size_t ws_size,
                              hipStream_t stream) {
  const float* x       = (const float*)d_in[0];
  const int*   met_sub = (const int*)d_in[1];
  const int*   rxn_sub = (const int*)d_in[2];
  const float* sto_sub = (const float*)d_in[3];
  const int*   met_all = (const int*)d_in[4];
  const int*   rxn_all = (const int*)d_in[5];
  const float* sto_all = (const float*)d_in[6];
  const float* W1    = (const float*)d_in[7];
  const float* b1    = (const float*)d_in[8];
  const float* W2    = (const float*)d_in[9];
  const float* b2    = (const float*)d_in[10];
  const float* W3    = (const float*)d_in[11];
  const float* b3    = (const float*)d_in[12];
  const float* W4    = (const float*)d_in[13];
  const float* b4    = (const float*)d_in[14];
  const float* log_k = (const float*)d_in[15];
  float* dxdt = (float*)d_out;

  char* ws = (char*)d_ws;
  size_t p = 0;
  auto alloc = [&](size_t bytes) -> void* {
    void* r = (void*)(ws + p);
    p += (bytes + 255) & ~(size_t)255;
    return r;
  };
  int*    off        = (int*)alloc(sizeof(int) * (N_RXN + 1));
  uint4*  wfh        = (uint4*)alloc(sizeof(uint4) * 512);
  uint4*  wfl        = (uint4*)alloc(sizeof(uint4) * 512);
  float*  b2w3       = (float*)alloc(sizeof(float) * 64);
  float*  v_pre      = (float*)alloc(sizeof(float) * N_RXN);
  float*  vfin       = (float*)alloc(sizeof(float) * N_RXN);
  float*  conc       = (float*)alloc(sizeof(float) * N_MET);
  float*  met_scale  = (float*)alloc(sizeof(float) * N_MET);
  int2*   edges8     = (int2*)alloc(sizeof(int2) * E_SUB);      // CSR {m, sto}
  int2*   bins_rxn   = (int2*)alloc(sizeof(int2) * E_SUB);      // rxn-binned staging
  int2*   bins_sub   = (int2*)alloc(sizeof(int2) * E_SUB);      // met-binned {mloc, val}
  int2*   bins       = (int2*)alloc(sizeof(int2) * E_ALL);      // met-binned {mloc, val}
  int*    rblk_cnt   = (int*)alloc(sizeof(int) * RNBINS * RPART_NBLK);
  int*    rblk_pref  = (int*)alloc(sizeof(int) * RNBINS * RPART_NBLK);
  int*    sblk_cnt   = (int*)alloc(sizeof(int) * NBINS * SPART_NBLK);
  int*    sblk_pref  = (int*)alloc(sizeof(int) * NBINS * SPART_NBLK);
  int*    blk_cnt    = (int*)alloc(sizeof(int) * NBINS * PART_NBLK);
  int*    blk_pref   = (int*)alloc(sizeof(int) * NBINS * PART_NBLK);
  int*    rbin_tot   = (int*)alloc(sizeof(int) * 512);
  int*    rbin_start = (int*)alloc(sizeof(int) * 512);
  int*    sbin_tot   = (int*)alloc(sizeof(int) * 512);
  int*    sbin_start = (int*)alloc(sizeof(int) * 512);
  int*    bin_tot    = (int*)alloc(sizeof(int) * 512);
  int*    bin_start  = (int*)alloc(sizeof(int) * 512);
  unsigned short* Thi = (unsigned short*)alloc(sizeof(unsigned short) * (size_t)N_RXN_PAD * 64);
  size_t tlo_bytes = sizeof(unsigned short) * (size_t)N_RXN_PAD * 64;
  int use_lo = (p + tlo_bytes <= ws_size) ? 1 : 0;
  unsigned short* Tlo = use_lo ? (unsigned short*)alloc(tlo_bytes) : Thi;
  (void)in_sizes; (void)n_in; (void)out_size;

  // no global memsets needed: every buffer is fully written before it is read

  k_pre<<<2, 256, 0, stream>>>(W2, W3, b2, wfh, wfl, b2w3);
  k_conc<<<(N_MET + 255) / 256, 256, 0, stream>>>(x, conc);

  // bin counts (all independent)
  k_rbc<<<RPART_NBLK, 256, 0, stream>>>(rxn_sub, rblk_cnt);
  k_bc_sub<<<SPART_NBLK, 256, 0, stream>>>(met_sub, sblk_cnt);
  k_bc_all<<<PART_NBLK, 256, 0, stream>>>(met_all, blk_cnt);
  k_bscan1<<<RNBINS, 256, 0, stream>>>(rblk_cnt, rblk_pref, rbin_tot, RPART_NBLK);
  k_bscan1<<<NBINS, 256, 0, stream>>>(sblk_cnt, sblk_pref, sbin_tot, SPART_NBLK);
  k_bscan1<<<NBINS, 256, 0, stream>>>(blk_cnt, blk_pref, bin_tot, PART_NBLK);
  k_bscan2<<<1, 512, 0, stream>>>(rbin_tot, rbin_start, RNBINS);
  k_bscan2<<<1, 512, 0, stream>>>(sbin_tot, sbin_start, NBINS);
  k_bscan2<<<1, 512, 0, stream>>>(bin_tot, bin_start, NBINS);

  // CSR build (counting sort, no global atomics)
  k_rpart<<<RPART_NBLK, 256, 0, stream>>>(rxn_sub, met_sub, sto_sub,
                                          rblk_pref, rbin_start, bins_rxn);
  k_rbin<<<RNBINS, 256, 0, stream>>>(bins_rxn, rbin_start, rbin_tot, edges8, off);

  // MLP phases
  k_edge<<<(N_RXN + RXN_PER_BLK - 1) / RXN_PER_BLK, THREADS, 0, stream>>>(
      off, edges8, conc, W1, b1, Thi, Tlo, use_lo);
  k_mv<<<(N_RXN + MV_RPB - 1) / MV_RPB, 256, 0, stream>>>(
      off, Thi, Tlo, wfh, wfl, b2w3, b3, W4, b4, log_k, use_lo, v_pre);

  // consumption totals -> met_scale (binned, fused scale)
  k_part_sub<<<SPART_NBLK, 256, 0, stream>>>(met_sub, rxn_sub, sto_sub, v_pre,
                                             sblk_pref, sbin_start, bins_sub);
  k_bins_sub<<<NBINS, 256, 0, stream>>>(bins_sub, sbin_start, sbin_tot, conc, met_scale);

  // rxn scale + final v
  k_rscale<<<(N_RXN + MV_RPB - 1) / MV_RPB, 256, 0, stream>>>(
      off, edges8, met_scale, v_pre, vfin);

  // dxdt (binned)
  k_part<<<PART_NBLK, 256, 0, stream>>>(met_all, rxn_all, sto_all, vfin,
                                        blk_pref, bin_start, bins);
  k_bins<<<NBINS, 256, 0, stream>>>(bins, bin_start, bin_tot, dxdt);
}

// Round 11
// 516.714 us; speedup vs baseline: 1.4981x; 1.1566x over previous
//
#include <hip/hip_runtime.h>

#define N_MET 250000
#define N_RXN 500000
#define N_RXN_PAD 500032   // padded rows for T so MFMA tail tiles stay in-bounds
#define E_SUB 2000000
#define E_ALL 4000000
#define DT 0.01f

#define RXN_PER_BLK 256
#define THREADS 256
#define EDGE_CAP 1536   // k_edge LDS staging cap; global fallback below

#define MV_RPB 64       // k_mv reactions per block (4 waves x 16)

// ---- binning geometry ----
#define BINSZ 1024
#define NBINS ((N_MET + BINSZ - 1) / BINSZ)                 // 245
#define PART_EPB 4096
#define PART_NBLK ((E_ALL + PART_EPB - 1) / PART_EPB)       // 977
#define SPART_NBLK ((E_SUB + PART_EPB - 1) / PART_EPB)      // 489
#define RBINSZ 1024
#define RNBINS ((N_RXN + RBINSZ - 1) / RBINSZ)              // 489
#define RPART_NBLK ((E_SUB + PART_EPB - 1) / PART_EPB)      // 489
#define RBIN_CAP 6144   // Poisson(4096) + ~30 sigma; global fallback below

typedef int v4i __attribute__((ext_vector_type(4)));
typedef float v4f __attribute__((ext_vector_type(4)));
typedef short bf16x8 __attribute__((ext_vector_type(8)));
typedef float f32x4 __attribute__((ext_vector_type(4)));

static __device__ __forceinline__ float fast_tanh(float x) {
  float e = __expf(x + x);
  return 1.0f - __fdividef(2.0f, e + 1.0f);
}

static __device__ __forceinline__ int bcast_i(int v, int lane) {
  return __builtin_amdgcn_readlane(v, lane);
}

static __device__ __forceinline__ unsigned short bf16_rn(float f) {
  unsigned u = __float_as_uint(f);
  unsigned r = u + 0x7FFFu + ((u >> 16) & 1u);
  return (unsigned short)(r >> 16);
}

// ---- precompute MFMA B-fragments of W23 = W2@W3 (bf16 hi/lo) and b2@W3 ----
__global__ void k_pre(const float* __restrict__ W2, const float* __restrict__ W3,
                      const float* __restrict__ b2,
                      uint4* __restrict__ wfh, uint4* __restrict__ wfl,
                      float* __restrict__ b2w3) {
  int tid = blockIdx.x * blockDim.x + threadIdx.x;
  if (tid < 512) {
    int lane = tid & 63, jt = (tid >> 6) & 3, ks = tid >> 8;
    int jj = jt * 16 + (lane & 15);
    unsigned short h[8], l[8];
    #pragma unroll
    for (int t = 0; t < 8; ++t) {
      int kk = ks * 32 + (lane >> 4) * 8 + t;
      float w = 0.f;
      #pragma unroll
      for (int m = 0; m < 32; ++m) w = fmaf(W2[kk * 32 + m], W3[m * 64 + jj], w);
      h[t] = bf16_rn(w);
      float hf = __uint_as_float(((unsigned)h[t]) << 16);
      l[t] = bf16_rn(w - hf);
    }
    uint4 H, L;
    H.x = (unsigned)h[0] | ((unsigned)h[1] << 16);
    H.y = (unsigned)h[2] | ((unsigned)h[3] << 16);
    H.z = (unsigned)h[4] | ((unsigned)h[5] << 16);
    H.w = (unsigned)h[6] | ((unsigned)h[7] << 16);
    L.x = (unsigned)l[0] | ((unsigned)l[1] << 16);
    L.y = (unsigned)l[2] | ((unsigned)l[3] << 16);
    L.z = (unsigned)l[4] | ((unsigned)l[5] << 16);
    L.w = (unsigned)l[6] | ((unsigned)l[7] << 16);
    int idx = (ks * 4 + jt) * 64 + lane;
    wfh[idx] = H; wfl[idx] = L;
  }
  if (tid < 64) {
    float t = 0.f;
    #pragma unroll
    for (int m = 0; m < 32; ++m) t = fmaf(b2[m], W3[m * 64 + tid], t);
    b2w3[tid] = t;
  }
}

// ---- dense conc extraction ----
__global__ void k_conc(const float* __restrict__ x, float* __restrict__ conc) {
  int m = blockIdx.x * blockDim.x + threadIdx.x;
  if (m < N_MET) conc[m] = __builtin_nontemporal_load(x + m * 8 + 3);
}

// ==== bin-count / scan kernels (LDS histograms, zero global atomics) ====

template <int NB>
static __device__ __forceinline__ void bc_body(const int* __restrict__ keys, int nkeys,
                                               int* __restrict__ blk_cnt, int nblk) {
  __shared__ int cnt[NB];
  int b = blockIdx.x, t = threadIdx.x;
  for (int i = t; i < NB; i += 256) cnt[i] = 0;
  __syncthreads();
  int base = b * PART_EPB;
  #pragma unroll
  for (int i = 0; i < PART_EPB / 256; ++i) {
    int e = base + i * 256 + t;
    if (e < nkeys) atomicAdd(&cnt[__builtin_nontemporal_load(keys + e) >> 10], 1);
  }
  __syncthreads();
  for (int i = t; i < NB; i += 256) blk_cnt[i * nblk + b] = cnt[i];
}

__global__ __launch_bounds__(256) void k_bc_all(const int* __restrict__ met_all,
                                                int* __restrict__ blk_cnt) {
  bc_body<NBINS>(met_all, E_ALL, blk_cnt, PART_NBLK);
}
__global__ __launch_bounds__(256) void k_bc_sub(const int* __restrict__ met_sub,
                                                int* __restrict__ blk_cnt) {
  bc_body<NBINS>(met_sub, E_SUB, blk_cnt, SPART_NBLK);
}
__global__ __launch_bounds__(256) void k_rbc(const int* __restrict__ rxn_sub,
                                             int* __restrict__ blk_cnt) {
  bc_body<RNBINS>(rxn_sub, E_SUB, blk_cnt, RPART_NBLK);
}

__global__ __launch_bounds__(256) void k_bscan1(const int* __restrict__ blk_cnt,
                                                int* __restrict__ blk_pref,
                                                int* __restrict__ bin_tot, int nblk) {
  __shared__ int ss[256];
  int j = blockIdx.x, t = threadIdx.x;
  int carry = 0;
  for (int c = 0; c < nblk; c += 256) {
    int idx = c + t;
    int v = (idx < nblk) ? blk_cnt[j * nblk + idx] : 0;
    ss[t] = v; __syncthreads();
    for (int d = 1; d < 256; d <<= 1) {
      int a = (t >= d) ? ss[t - d] : 0;
      __syncthreads();
      ss[t] += a;
      __syncthreads();
    }
    if (idx < nblk) blk_pref[j * nblk + idx] = carry + ss[t] - v;
    carry += ss[255];
    __syncthreads();
  }
  if (t == 0) bin_tot[j] = carry;
}

__global__ __launch_bounds__(512) void k_bscan2(const int* __restrict__ bin_tot,
                                                int* __restrict__ bin_start, int n) {
  __shared__ int ss[512];
  int t = threadIdx.x;
  int v = (t < n) ? bin_tot[t] : 0;
  ss[t] = v; __syncthreads();
  for (int d = 1; d < 512; d <<= 1) {
    int a = (t >= d) ? ss[t - d] : 0;
    __syncthreads();
    ss[t] += a;
    __syncthreads();
  }
  if (t < n) bin_start[t] = ss[t] - v;
}

// ==== block-locally-sorted partition: records leave as contiguous bursts ====
// Pass A: count keys/bin (keys cached in VGPRs). Scan -> local starts, global offsets.
// Pass B: build records into bin-ordered LDS buffer. Pass C: ordered burst copy out.
template <int NB, typename MakeRec>
static __device__ __forceinline__ void part_sorted(
    const int* __restrict__ keys, int nkeys, int nblk,
    const int* __restrict__ blk_pref, const int* __restrict__ bin_start,
    int2* __restrict__ out, MakeRec make) {
  __shared__ int2 ordered[PART_EPB];            // 32 KB
  __shared__ unsigned short binb[PART_EPB];     // 8 KB
  __shared__ int cnt[NB];
  __shared__ int gofs[NB];
  __shared__ int ss[256];
  int b = blockIdx.x, t = threadIdx.x;
  for (int i = t; i < NB; i += 256) cnt[i] = 0;
  __syncthreads();
  int base = b * PART_EPB;
  int kbuf[PART_EPB / 256];
  #pragma unroll
  for (int i = 0; i < PART_EPB / 256; ++i) {
    int e = base + i * 256 + t;
    kbuf[i] = (e < nkeys) ? __builtin_nontemporal_load(keys + e) : -1;
    if (kbuf[i] >= 0) atomicAdd(&cnt[kbuf[i] >> 10], 1);
  }
  __syncthreads();
  // exclusive scan of cnt; cnt becomes the running cursor (lstart), gofs = global - lstart
  int nloc = 0;
  for (int c = 0; c < NB; c += 256) {
    int idx = c + t;
    int v = (idx < NB) ? cnt[idx] : 0;
    ss[t] = v; __syncthreads();
    for (int d = 1; d < 256; d <<= 1) {
      int a = (t >= d) ? ss[t - d] : 0;
      __syncthreads();
      ss[t] += a;
      __syncthreads();
    }
    int tot = ss[255];
    if (idx < NB) {
      int ls = nloc + ss[t] - v;
      cnt[idx] = ls;  // becomes cursor
      gofs[idx] = bin_start[idx] + blk_pref[idx * nblk + b] - ls;
    }
    nloc += tot;
    __syncthreads();
  }
  // pass B: place records bin-ordered in LDS
  #pragma unroll
  for (int i = 0; i < PART_EPB / 256; ++i) {
    int k = kbuf[i];
    if (k >= 0) {
      int e = base + i * 256 + t;
      int bin = k >> 10;
      int2 rec = make(e, k);
      int pos = atomicAdd(&cnt[bin], 1);  // LDS atomic
      ordered[pos] = rec;
      binb[pos] = (unsigned short)bin;
    }
  }
  __syncthreads();
  // pass C: ordered, coalesced burst copy
  for (int i = t; i < nloc; i += 256) {
    int2 rec = ordered[i];
    out[gofs[binb[i]] + i] = rec;
  }
}

// CSR partition: packed {rloc:10|m:18, sto} by rxn-bin
__global__ __launch_bounds__(256) void k_rpart(
    const int* __restrict__ rxn_sub, const int* __restrict__ met_sub,
    const float* __restrict__ sto_sub,
    const int* __restrict__ blk_pref, const int* __restrict__ bin_start,
    int2* __restrict__ bins_rxn) {
  part_sorted<RNBINS>(rxn_sub, E_SUB, RPART_NBLK, blk_pref, bin_start, bins_rxn,
    [=] __device__ (int e, int k) {
      int m = __builtin_nontemporal_load(met_sub + e);
      float st = __builtin_nontemporal_load(sto_sub + e);
      int2 rec; rec.x = ((k & (RBINSZ - 1)) << 18) | m; rec.y = __float_as_int(st);
      return rec;
    });
}

// consumption partition: {mloc, sto*v_pre[r]*DT} by met-bin
__global__ __launch_bounds__(256) void k_part_sub(
    const int* __restrict__ met_sub, const int* __restrict__ rxn_sub,
    const float* __restrict__ sto_sub, const float* __restrict__ v_pre,
    const int* __restrict__ blk_pref, const int* __restrict__ bin_start,
    int2* __restrict__ bins_sub) {
  part_sorted<NBINS>(met_sub, E_SUB, SPART_NBLK, blk_pref, bin_start, bins_sub,
    [=] __device__ (int e, int k) {
      int r = __builtin_nontemporal_load(rxn_sub + e);
      float st = __builtin_nontemporal_load(sto_sub + e);
      float val = st * v_pre[r] * DT;
      int2 rec; rec.x = k & (BINSZ - 1); rec.y = __float_as_int(val);
      return rec;
    });
}

// dxdt partition: {mloc, sto*vfin[r]} by met-bin
__global__ __launch_bounds__(256) void k_part(
    const int* __restrict__ met_all, const int* __restrict__ rxn_all,
    const float* __restrict__ sto_all, const float* __restrict__ vfin,
    const int* __restrict__ blk_pref, const int* __restrict__ bin_start,
    int2* __restrict__ bins) {
  part_sorted<NBINS>(met_all, E_ALL, PART_NBLK, blk_pref, bin_start, bins,
    [=] __device__ (int e, int k) {
      int r = __builtin_nontemporal_load(rxn_all + e);
      float st = __builtin_nontemporal_load(sto_all + e);
      float val = st * vfin[r];
      int2 rec; rec.x = k & (BINSZ - 1); rec.y = __float_as_int(val);
      return rec;
    });
}

// ==== CSR per-bin local sort -> edges8 CSR order + off[] ====
__global__ __launch_bounds__(256) void k_rbin(
    const int2* __restrict__ bins_rxn, const int* __restrict__ rbin_start,
    const int* __restrict__ rbin_tot, int2* __restrict__ edges8, int* __restrict__ off) {
  __shared__ int2 stage[RBIN_CAP];   // 48 KB
  __shared__ int lcnt[RBINSZ];
  __shared__ int lcur[RBINSZ];
  __shared__ int ss[256];
  int j = blockIdx.x, t = threadIdx.x;
  int base = rbin_start[j], n = rbin_tot[j];
  for (int i = t; i < RBINSZ; i += 256) lcnt[i] = 0;
  __syncthreads();
  bool fits = (n <= RBIN_CAP);
  if (fits) {
    for (int i = t; i < n; i += 256) {
      int2 rec = bins_rxn[base + i];
      stage[i] = rec;
      atomicAdd(&lcnt[((unsigned)rec.x) >> 18], 1);
    }
  } else {
    for (int i = t; i < n; i += 256) {
      int2 rec = bins_rxn[base + i];
      atomicAdd(&lcnt[((unsigned)rec.x) >> 18], 1);
    }
  }
  __syncthreads();
  int s0 = lcnt[4 * t], s1 = lcnt[4 * t + 1], s2 = lcnt[4 * t + 2], s3 = lcnt[4 * t + 3];
  int tsum = s0 + s1 + s2 + s3;
  ss[t] = tsum; __syncthreads();
  for (int d = 1; d < 256; d <<= 1) {
    int a = (t >= d) ? ss[t - d] : 0;
    __syncthreads();
    ss[t] += a;
    __syncthreads();
  }
  int run = ss[t] - tsum;
  lcur[4 * t] = run;
  lcur[4 * t + 1] = run + s0;
  lcur[4 * t + 2] = run + s0 + s1;
  lcur[4 * t + 3] = run + s0 + s1 + s2;
  __syncthreads();
  int R0 = j * RBINSZ;
  for (int rl = t; rl < RBINSZ; rl += 256) {
    int r = R0 + rl;
    if (r < N_RXN) off[r] = base + lcur[rl];
  }
  if (j == 0 && t == 0) off[N_RXN] = E_SUB;
  __syncthreads();
  if (fits) {
    for (int i = t; i < n; i += 256) {
      int2 rec = stage[i];
      int pos = atomicAdd(&lcur[((unsigned)rec.x) >> 18], 1);
      int2 out; out.x = rec.x & 0x3FFFF; out.y = rec.y;
      edges8[base + pos] = out;
    }
  } else {
    for (int i = t; i < n; i += 256) {
      int2 rec = bins_rxn[base + i];
      int pos = atomicAdd(&lcur[((unsigned)rec.x) >> 18], 1);
      int2 out; out.x = rec.x & 0x3FFFF; out.y = rec.y;
      edges8[base + pos] = out;
    }
  }
}

// ---- k_edge: wave-per-reaction edge tanh-sum; T -> bf16 hi/lo, row-major [r][64] ----
static __device__ __forceinline__ float edge_sum_lds(int o0, int o1, int estart,
                                                     const float2* ep,
                                                     float w1x, float w1y, float b1j) {
  float T0 = 0.f, T1 = 0.f;
  int c = o0;
  for (; c + 1 < o1; c += 2) {
    float2 e0 = ep[c - estart];
    float2 e1 = ep[c + 1 - estart];
    T0 += fast_tanh(fmaf(e0.x, w1x, fmaf(e0.y, w1y, b1j)));
    T1 += fast_tanh(fmaf(e1.x, w1x, fmaf(e1.y, w1y, b1j)));
  }
  if (c < o1) {
    float2 e0 = ep[c - estart];
    T0 += fast_tanh(fmaf(e0.x, w1x, fmaf(e0.y, w1y, b1j)));
  }
  return T0 + T1;
}

static __device__ __forceinline__ float edge_sum_glob(int o0, int o1,
                                                      const int2* edges8,
                                                      const float* conc,
                                                      float w1x, float w1y, float b1j) {
  float T = 0.f;
  for (int c = o0; c < o1; ++c) {
    int2 rec = edges8[c];
    float cc = conc[rec.x];
    T += fast_tanh(fmaf(cc, w1x, fmaf(__int_as_float(rec.y), w1y, b1j)));
  }
  return T;
}

__global__ __launch_bounds__(THREADS) void k_edge(
    const int* __restrict__ off, const int2* __restrict__ edges8,
    const float* __restrict__ conc,
    const float* __restrict__ W1, const float* __restrict__ b1,
    unsigned short* __restrict__ Thi, unsigned short* __restrict__ Tlo, int use_lo) {
  __shared__ int off_s[RXN_PER_BLK + 1];
  __shared__ float2 se[EDGE_CAP];

  int tid = threadIdx.x;
  int lane = tid & 63;
  int wv = tid >> 6;
  int R0 = blockIdx.x * RXN_PER_BLK;

  for (int i = tid; i <= RXN_PER_BLK; i += THREADS) {
    int r = R0 + i;
    off_s[i] = off[r > N_RXN ? N_RXN : r];
  }
  __syncthreads();
  int estart = off_s[0];
  int nE = off_s[RXN_PER_BLK] - estart;
  bool fits = (nE <= EDGE_CAP);
  if (fits) {
    for (int i = tid; i < nE; i += THREADS) {
      int2 rec = edges8[estart + i];
      se[i] = make_float2(conc[rec.x], __int_as_float(rec.y));
    }
  }

  float w1x = W1[lane], w1y = W1[64 + lane], b1j = b1[lane];

  int rbase = R0 + wv * 64;
  int o0l = off_s[wv * 64 + lane];
  int o1l = off_s[wv * 64 + lane + 1];

  __syncthreads();

  #pragma clang loop unroll(disable)
  for (int i = 0; i < 64; ++i) {
    int r = rbase + i;
    if (r >= N_RXN) break;  // uniform
    int o0 = bcast_i(o0l, i), o1 = bcast_i(o1l, i);
    float T = fits ? edge_sum_lds(o0, o1, estart, se, w1x, w1y, b1j)
                   : edge_sum_glob(o0, o1, edges8, conc, w1x, w1y, b1j);
    unsigned short hi = bf16_rn(T);
    Thi[r * 64 + lane] = hi;
    if (use_lo) {
      float hf = __uint_as_float(((unsigned)hi) << 16);
      Tlo[r * 64 + lane] = bf16_rn(T - hf);
    }
  }
}

// ---- k_mv: U = T @ W23 via MFMA (bf16 hi/lo), epilogue only (no atomics) ----
__global__ __launch_bounds__(256) void k_mv(
    const int* __restrict__ off,
    const unsigned short* __restrict__ Thi, const unsigned short* __restrict__ Tlo,
    const uint4* __restrict__ wfh, const uint4* __restrict__ wfl,
    const float* __restrict__ b2w3, const float* __restrict__ b3,
    const float* __restrict__ W4, const float* __restrict__ b4,
    const float* __restrict__ log_k, int use_lo, float* __restrict__ v_pre) {
  __shared__ int soff[MV_RPB + 1];
  int tid = threadIdx.x, lane = tid & 63, w = tid >> 6;
  int B0 = blockIdx.x * MV_RPB;
  for (int i = tid; i <= MV_RPB; i += 256) {
    int r = B0 + i;
    soff[i] = off[r > N_RXN ? N_RXN : r];
  }
  __syncthreads();

  int R0 = B0 + w * 16;
  int col = lane & 15, rowg = lane >> 4;

  bf16x8 ah[2], al[2];
  {
    int rowelem = (R0 + col) * 64 + rowg * 8;
    const uint4* ph = (const uint4*)Thi;
    ah[0] = __builtin_bit_cast(bf16x8, ph[rowelem >> 3]);
    ah[1] = __builtin_bit_cast(bf16x8, ph[(rowelem + 32) >> 3]);
    if (use_lo) {
      const uint4* pl = (const uint4*)Tlo;
      al[0] = __builtin_bit_cast(bf16x8, pl[rowelem >> 3]);
      al[1] = __builtin_bit_cast(bf16x8, pl[(rowelem + 32) >> 3]);
    }
  }

  f32x4 acc[4];
  #pragma unroll
  for (int jt = 0; jt < 4; ++jt) acc[jt] = (f32x4){0.f, 0.f, 0.f, 0.f};

  #pragma unroll
  for (int jt = 0; jt < 4; ++jt) {
    #pragma unroll
    for (int ks = 0; ks < 2; ++ks) {
      int bidx = (ks * 4 + jt) * 64 + lane;
      bf16x8 bh = __builtin_bit_cast(bf16x8, wfh[bidx]);
      acc[jt] = __builtin_amdgcn_mfma_f32_16x16x32_bf16(ah[ks], bh, acc[jt], 0, 0, 0);
      if (use_lo) {
        bf16x8 bl = __builtin_bit_cast(bf16x8, wfl[bidx]);
        acc[jt] = __builtin_amdgcn_mfma_f32_16x16x32_bf16(ah[ks], bl, acc[jt], 0, 0, 0);
        acc[jt] = __builtin_amdgcn_mfma_f32_16x16x32_bf16(al[ks], bh, acc[jt], 0, 0, 0);
      }
    }
  }

  float w4c[4], bwc[4], b3c[4];
  #pragma unroll
  for (int jt = 0; jt < 4; ++jt) {
    int jj = jt * 16 + col;
    w4c[jt] = W4[jj]; bwc[jt] = b2w3[jj]; b3c[jt] = b3[jj];
  }
  float b40 = b4[0];

  float nq[4];
  #pragma unroll
  for (int q = 0; q < 4; ++q) {
    int idx = w * 16 + rowg * 4 + q;
    nq[q] = (float)(soff[idx + 1] - soff[idx]);
  }

  #pragma unroll
  for (int q = 0; q < 4; ++q) {
    float s = 0.f;
    #pragma unroll
    for (int jt = 0; jt < 4; ++jt) {
      float u = acc[jt][q] + nq[q] * bwc[jt] + b3c[jt];
      s += fast_tanh(u) * w4c[jt];
    }
    s += __shfl_xor(s, 1, 64);
    s += __shfl_xor(s, 2, 64);
    s += __shfl_xor(s, 4, 64);
    s += __shfl_xor(s, 8, 64);
    if (col == 0) {
      int r = R0 + rowg * 4 + q;
      float lk = (r < N_RXN) ? log_k[r] : 0.f;
      float racc = s + b40;
      float k10 = __expf(lk * 2.3025850929940457f);
      float sp = (racc > 15.f) ? racc : __logf(1.f + __expf(racc));
      if (r < N_RXN) v_pre[r] = k10 * sp;
    }
  }
}

// accumulate consumption totals per bin + fused met_scale
__global__ __launch_bounds__(256) void k_bins_sub(
    const int2* __restrict__ bins_sub, const int* __restrict__ bin_start,
    const int* __restrict__ bin_tot, const float* __restrict__ conc,
    float* __restrict__ met_scale) {
  __shared__ float acc[BINSZ];
  int j = blockIdx.x, t = threadIdx.x;
  for (int i = t; i < BINSZ; i += 256) acc[i] = 0.f;
  __syncthreads();
  int s0 = bin_start[j], n = bin_tot[j];
  for (int i = t; i < n; i += 256) {
    int2 rec = bins_sub[s0 + i];
    atomicAdd(&acc[rec.x], __int_as_float(rec.y));  // LDS fp32 atomic
  }
  __syncthreads();
  int m0 = j * BINSZ;
  for (int i = t; i < BINSZ; i += 256) {
    int m = m0 + i;
    if (m < N_MET) {
      float tot = acc[i];
      met_scale[m] = (tot > 1e-12f) ? fminf(conc[m] / tot, 1.0f) : 1.0f;
    }
  }
}

// ---- k_rscale: per-rxn min over CSR slice (4 lanes/rxn), fused vfin write ----
__global__ __launch_bounds__(256) void k_rscale(
    const int* __restrict__ off, const int2* __restrict__ edges8,
    const float* __restrict__ met_scale, const float* __restrict__ v_pre,
    float* __restrict__ vfin) {
  __shared__ int soff[MV_RPB + 1];
  int tid = threadIdx.x, lane = tid & 63, w = tid >> 6;
  int B0 = blockIdx.x * MV_RPB;
  for (int i = tid; i <= MV_RPB; i += 256) {
    int r = B0 + i;
    soff[i] = off[r > N_RXN ? N_RXN : r];
  }
  __syncthreads();

  int rloc = w * 16 + (lane >> 2);
  int o0 = soff[rloc], o1 = soff[rloc + 1];
  float sc = 1.0f;
  for (int c = o0 + (lane & 3); c < o1; c += 4) {
    sc = fminf(sc, met_scale[edges8[c].x]);
  }
  sc = fminf(sc, __shfl_xor(sc, 1, 64));
  sc = fminf(sc, __shfl_xor(sc, 2, 64));
  if ((lane & 3) == 0) {
    int r = B0 + rloc;
    if (r < N_RXN) vfin[r] = v_pre[r] * sc;
  }
}

__global__ __launch_bounds__(256) void k_bins(const int2* __restrict__ bins,
                                              const int* __restrict__ bin_start,
                                              const int* __restrict__ bin_tot,
                                              float* __restrict__ dxdt) {
  __shared__ float acc[BINSZ];
  int j = blockIdx.x, t = threadIdx.x;
  for (int i = t; i < BINSZ; i += 256) acc[i] = 0.f;
  __syncthreads();
  int s0 = bin_start[j], n = bin_tot[j];
  for (int i = t; i < n; i += 256) {
    int2 rec = bins[s0 + i];
    atomicAdd(&acc[rec.x], __int_as_float(rec.y));  // LDS fp32 atomic
  }
  __syncthreads();
  int m0 = j * BINSZ;
  for (int i = t; i < BINSZ; i += 256) {
    int m = m0 + i;
    if (m < N_MET) dxdt[m] = acc[i];
  }
}

extern "C" void kernel_launch(void* const* d_in, const int* in_sizes, int n_in,
                              void* d_out, int out_size, void* d_ws, size_t ws_size,
                              hipStream_t stream) {
  const float* x       = (const float*)d_in[0];
  const int*   met_sub = (const int*)d_in[1];
  const int*   rxn_sub = (const int*)d_in[2];
  const float* sto_sub = (const float*)d_in[3];
  const int*   met_all = (const int*)d_in[4];
  const int*   rxn_all = (const int*)d_in[5];
  const float* sto_all = (const float*)d_in[6];
  const float* W1    = (const float*)d_in[7];
  const float* b1    = (const float*)d_in[8];
  const float* W2    = (const float*)d_in[9];
  const float* b2    = (const float*)d_in[10];
  const float* W3    = (const float*)d_in[11];
  const float* b3    = (const float*)d_in[12];
  const float* W4    = (const float*)d_in[13];
  const float* b4    = (const float*)d_in[14];
  const float* log_k = (const float*)d_in[15];
  float* dxdt = (float*)d_out;

  char* ws = (char*)d_ws;
  size_t p = 0;
  auto alloc = [&](size_t bytes) -> void* {
    void* r = (void*)(ws + p);
    p += (bytes + 255) & ~(size_t)255;
    return r;
  };
  int*    off        = (int*)alloc(sizeof(int) * (N_RXN + 1));
  uint4*  wfh        = (uint4*)alloc(sizeof(uint4) * 512);
  uint4*  wfl        = (uint4*)alloc(sizeof(uint4) * 512);
  float*  b2w3       = (float*)alloc(sizeof(float) * 64);
  float*  v_pre      = (float*)alloc(sizeof(float) * N_RXN);
  float*  vfin       = (float*)alloc(sizeof(float) * N_RXN);
  float*  conc       = (float*)alloc(sizeof(float) * N_MET);
  float*  met_scale  = (float*)alloc(sizeof(float) * N_MET);
  int2*   edges8     = (int2*)alloc(sizeof(int2) * E_SUB);      // CSR {m, sto}
  int2*   bins_rxn   = (int2*)alloc(sizeof(int2) * E_SUB);      // rxn-binned staging
  int2*   bins_sub   = (int2*)alloc(sizeof(int2) * E_SUB);      // met-binned {mloc, val}
  int2*   bins       = (int2*)alloc(sizeof(int2) * E_ALL);      // met-binned {mloc, val}
  int*    rblk_cnt   = (int*)alloc(sizeof(int) * RNBINS * RPART_NBLK);
  int*    rblk_pref  = (int*)alloc(sizeof(int) * RNBINS * RPART_NBLK);
  int*    sblk_cnt   = (int*)alloc(sizeof(int) * NBINS * SPART_NBLK);
  int*    sblk_pref  = (int*)alloc(sizeof(int) * NBINS * SPART_NBLK);
  int*    blk_cnt    = (int*)alloc(sizeof(int) * NBINS * PART_NBLK);
  int*    blk_pref   = (int*)alloc(sizeof(int) * NBINS * PART_NBLK);
  int*    rbin_tot   = (int*)alloc(sizeof(int) * 512);
  int*    rbin_start = (int*)alloc(sizeof(int) * 512);
  int*    sbin_tot   = (int*)alloc(sizeof(int) * 512);
  int*    sbin_start = (int*)alloc(sizeof(int) * 512);
  int*    bin_tot    = (int*)alloc(sizeof(int) * 512);
  int*    bin_start  = (int*)alloc(sizeof(int) * 512);
  unsigned short* Thi = (unsigned short*)alloc(sizeof(unsigned short) * (size_t)N_RXN_PAD * 64);
  size_t tlo_bytes = sizeof(unsigned short) * (size_t)N_RXN_PAD * 64;
  int use_lo = (p + tlo_bytes <= ws_size) ? 1 : 0;
  unsigned short* Tlo = use_lo ? (unsigned short*)alloc(tlo_bytes) : Thi;
  (void)in_sizes; (void)n_in; (void)out_size;

  // no global memsets needed: every buffer is fully written before it is read

  k_pre<<<2, 256, 0, stream>>>(W2, W3, b2, wfh, wfl, b2w3);
  k_conc<<<(N_MET + 255) / 256, 256, 0, stream>>>(x, conc);

  // bin counts (all independent)
  k_rbc<<<RPART_NBLK, 256, 0, stream>>>(rxn_sub, rblk_cnt);
  k_bc_sub<<<SPART_NBLK, 256, 0, stream>>>(met_sub, sblk_cnt);
  k_bc_all<<<PART_NBLK, 256, 0, stream>>>(met_all, blk_cnt);
  k_bscan1<<<RNBINS, 256, 0, stream>>>(rblk_cnt, rblk_pref, rbin_tot, RPART_NBLK);
  k_bscan1<<<NBINS, 256, 0, stream>>>(sblk_cnt, sblk_pref, sbin_tot, SPART_NBLK);
  k_bscan1<<<NBINS, 256, 0, stream>>>(blk_cnt, blk_pref, bin_tot, PART_NBLK);
  k_bscan2<<<1, 512, 0, stream>>>(rbin_tot, rbin_start, RNBINS);
  k_bscan2<<<1, 512, 0, stream>>>(sbin_tot, sbin_start, NBINS);
  k_bscan2<<<1, 512, 0, stream>>>(bin_tot, bin_start, NBINS);

  // CSR build (counting sort, no global atomics)
  k_rpart<<<RPART_NBLK, 256, 0, stream>>>(rxn_sub, met_sub, sto_sub,
                                          rblk_pref, rbin_start, bins_rxn);
  k_rbin<<<RNBINS, 256, 0, stream>>>(bins_rxn, rbin_start, rbin_tot, edges8, off);

  // MLP phases
  k_edge<<<(N_RXN + RXN_PER_BLK - 1) / RXN_PER_BLK, THREADS, 0, stream>>>(
      off, edges8, conc, W1, b1, Thi, Tlo, use_lo);
  k_mv<<<(N_RXN + MV_RPB - 1) / MV_RPB, 256, 0, stream>>>(
      off, Thi, Tlo, wfh, wfl, b2w3, b3, W4, b4, log_k, use_lo, v_pre);

  // consumption totals -> met_scale (binned, fused scale)
  k_part_sub<<<SPART_NBLK, 256, 0, stream>>>(met_sub, rxn_sub, sto_sub, v_pre,
                                             sblk_pref, sbin_start, bins_sub);
  k_bins_sub<<<NBINS, 256, 0, stream>>>(bins_sub, sbin_start, sbin_tot, conc, met_scale);

  // rxn scale + final v
  k_rscale<<<(N_RXN + MV_RPB - 1) / MV_RPB, 256, 0, stream>>>(
      off, edges8, met_scale, v_pre, vfin);

  // dxdt (binned)
  k_part<<<PART_NBLK, 256, 0, stream>>>(met_all, rxn_all, sto_all, vfin,
                                        blk_pref, bin_start, bins);
  k_bins<<<NBINS, 256, 0, stream>>>(bins, bin_start, bin_tot, dxdt);
}